// Round 1
// baseline (17347.649 us; speedup 1.0000x reference)
//
#include <hip/hip_runtime.h>
#include <math.h>

// Problem constants
constexpr int Lc = 12, Bc = 2, Sc = 1024, Dc = 768, Hc = 12, Fc = 3072, Vc = 50257, DKc = 64;
constexpr int Tc = Bc * Sc;  // 2048 token rows

// ---------------- block reduction helpers (256 threads = 4 waves) ----------------
__device__ __forceinline__ float bred_sum(float v, volatile float* sb) {
#pragma unroll
  for (int o = 32; o; o >>= 1) v += __shfl_down(v, o);
  int w = threadIdx.x >> 6;
  __syncthreads();  // protect sb from previous use
  if ((threadIdx.x & 63) == 0) sb[w] = v;
  __syncthreads();
  return sb[0] + sb[1] + sb[2] + sb[3];
}

__device__ __forceinline__ float bred_max(float v, volatile float* sb) {
#pragma unroll
  for (int o = 32; o; o >>= 1) v = fmaxf(v, __shfl_down(v, o));
  int w = threadIdx.x >> 6;
  __syncthreads();
  if ((threadIdx.x & 63) == 0) sb[w] = v;
  __syncthreads();
  return fmaxf(fmaxf(sb[0], sb[1]), fmaxf(sb[2], sb[3]));
}

// ---------------- embedding + positional encoding ----------------
__global__ __launch_bounds__(256) void embed_kernel(const float* __restrict__ emb,
                                                    const int* __restrict__ x,
                                                    float* __restrict__ h) {
  int t = blockIdx.x;       // 0..T-1 (t = b*S + s)
  int s = t & (Sc - 1);     // position within sequence
  int tok = x[t];
  const float scale = 27.712812921102035f;  // sqrt(768)
  for (int d = threadIdx.x; d < Dc; d += 256) {
    int i = d >> 1;
    float div = __expf((float)(2 * i) * (-9.210340371976184f / (float)Dc));
    float ang = (float)s * div;
    float pe = (d & 1) ? cosf(ang) : sinf(ang);
    h[(size_t)t * Dc + d] = emb[(size_t)tok * Dc + d] * scale + pe;
  }
}

// ---------------- layernorm (torch-style: unbiased std, a*(x-m)/(std+eps)+b) ----------------
__global__ __launch_bounds__(256) void ln_kernel(const float* __restrict__ in,
                                                 const float* __restrict__ ga,
                                                 const float* __restrict__ be,
                                                 float* __restrict__ out) {
  __shared__ float sb[4];
  int t = blockIdx.x;
  const float* row = in + (size_t)t * Dc;
  int tid = threadIdx.x;
  float x0 = row[tid], x1 = row[tid + 256], x2 = row[tid + 512];
  float s = bred_sum(x0 + x1 + x2, sb);
  float mean = s * (1.0f / 768.0f);
  float d0 = x0 - mean, d1 = x1 - mean, d2 = x2 - mean;
  float vs = bred_sum(d0 * d0 + d1 * d1 + d2 * d2, sb);
  float inv = 1.0f / (sqrtf(vs * (1.0f / 767.0f)) + 1e-6f);
  float* orow = out + (size_t)t * Dc;
  orow[tid] = ga[tid] * d0 * inv + be[tid];
  orow[tid + 256] = ga[tid + 256] * d1 * inv + be[tid + 256];
  orow[tid + 512] = ga[tid + 512] * d2 * inv + be[tid + 512];
}

// ---------------- tiled fp32 GEMM ----------------
// C[M,N] = op( A[M,K] @ B ) ; NT=false: B is [K,N]; NT=true: B is [N,K] (B^T mult)
// Optional: +bias[n], ReLU, +resid[m,n]. 256 threads, each computes TMxTN.
template <int BM, int BN, bool NT, bool BIAS, bool RELU, bool RESID>
__global__ __launch_bounds__(256) void gemm_kernel(const float* __restrict__ A,
                                                   const float* __restrict__ Bm,
                                                   const float* __restrict__ bias,
                                                   const float* __restrict__ resid,
                                                   float* __restrict__ C,
                                                   int M, int N, int K) {
  constexpr int BK = 16;
  constexpr int TM = BM / 16;
  constexpr int TN = BN / 16;
  __shared__ float As[BK][BM + 4];
  __shared__ float Bs[BK][BN + 4];
  const int bm = blockIdx.y * BM;
  const int bn = blockIdx.x * BN;
  const int tid = threadIdx.x;
  const int tx = tid & 15, ty = tid >> 4;
  float acc[TM][TN] = {};

  for (int k0 = 0; k0 < K; k0 += BK) {
    // load A tile (BM x BK), transposed into As[k][m]
#pragma unroll
    for (int jj = 0; jj < TM / 4; ++jj) {
      int e = tid * TM + jj * 4;
      int m = e >> 4, kc = e & 15;
      float4 a4 = *(const float4*)&A[(size_t)(bm + m) * K + k0 + kc];
      As[kc][m] = a4.x; As[kc + 1][m] = a4.y; As[kc + 2][m] = a4.z; As[kc + 3][m] = a4.w;
    }
    // load B tile
    if (!NT) {
#pragma unroll
      for (int jj = 0; jj < TN / 4; ++jj) {
        int e = tid * TN + jj * 4;
        int kc = e / BN, n = e % BN;
        float4 b4 = *(const float4*)&Bm[(size_t)(k0 + kc) * N + bn + n];
        *(float4*)&Bs[kc][n] = b4;
      }
    } else {
#pragma unroll
      for (int jj = 0; jj < TN / 4; ++jj) {
        int e = tid * TN + jj * 4;
        int n = e >> 4, kc = e & 15;
        int gn = bn + n;
        float4 b4 = make_float4(0.f, 0.f, 0.f, 0.f);
        if (gn < N) b4 = *(const float4*)&Bm[(size_t)gn * K + k0 + kc];
        Bs[kc][n] = b4.x; Bs[kc + 1][n] = b4.y; Bs[kc + 2][n] = b4.z; Bs[kc + 3][n] = b4.w;
      }
    }
    __syncthreads();
#pragma unroll
    for (int kk = 0; kk < BK; ++kk) {
      float ar[TM], br[TN];
#pragma unroll
      for (int i = 0; i < TM; i += 4) {
        float4 t4 = *(const float4*)&As[kk][ty * TM + i];
        ar[i] = t4.x; ar[i + 1] = t4.y; ar[i + 2] = t4.z; ar[i + 3] = t4.w;
      }
#pragma unroll
      for (int j = 0; j < TN; j += 4) {
        float4 t4 = *(const float4*)&Bs[kk][tx * TN + j];
        br[j] = t4.x; br[j + 1] = t4.y; br[j + 2] = t4.z; br[j + 3] = t4.w;
      }
#pragma unroll
      for (int i = 0; i < TM; ++i)
#pragma unroll
        for (int j = 0; j < TN; ++j)
          acc[i][j] = fmaf(ar[i], br[j], acc[i][j]);
    }
    __syncthreads();
  }
  // epilogue
#pragma unroll
  for (int i = 0; i < TM; ++i) {
    int m = bm + ty * TM + i;
#pragma unroll
    for (int j = 0; j < TN; ++j) {
      int n = bn + tx * TN + j;
      if (NT && n >= N) continue;  // only the logits GEMM has ragged N
      float vv = acc[i][j];
      if (BIAS) vv += bias[n];
      if (RELU) vv = fmaxf(vv, 0.0f);
      if (RESID) vv += resid[(size_t)m * N + n];
      C[(size_t)m * N + n] = vv;
    }
  }
}

// ---------------- causal attention: one block per (b, h, q-row) ----------------
__global__ __launch_bounds__(256) void attn_kernel(const float* __restrict__ q,
                                                   const float* __restrict__ k,
                                                   const float* __restrict__ v,
                                                   float* __restrict__ o) {
  int bid = blockIdx.x;
  int qi = bid & (Sc - 1);
  int hb = bid >> 10;      // b*H + h
  int hh = hb % Hc;
  int b = hb / Hc;
  const int tid = threadIdx.x;

  __shared__ float qs[DKc];
  __shared__ float p[Sc];
  __shared__ float red[4];
  __shared__ float oacc[4][DKc];

  size_t rowbase = ((size_t)(b * Sc + qi)) * Dc + hh * DKc;
  if (tid < DKc) qs[tid] = q[rowbase + tid] * 0.125f;  // fold 1/sqrt(64)
  __syncthreads();

  int nk = qi + 1;
  float pmax = -1e30f;
  for (int j = tid; j < nk; j += 256) {
    const float* kr = k + ((size_t)(b * Sc + j)) * Dc + hh * DKc;
    float s = 0.f;
#pragma unroll
    for (int d = 0; d < DKc; d += 4) {
      float4 k4 = *(const float4*)&kr[d];
      s += qs[d] * k4.x + qs[d + 1] * k4.y + qs[d + 2] * k4.z + qs[d + 3] * k4.w;
    }
    p[j] = s;
    pmax = fmaxf(pmax, s);
  }
  pmax = bred_max(pmax, red);
  float psum = 0.f;
  for (int j = tid; j < nk; j += 256) {
    float e = __expf(p[j] - pmax);
    p[j] = e;
    psum += e;
  }
  psum = bred_sum(psum, red);  // also makes p[] visible to all threads
  float inv = 1.0f / psum;

  int g = tid >> 6, lane = tid & 63;
  float acc = 0.f;
  for (int j = g; j < nk; j += 4)
    acc += p[j] * v[((size_t)(b * Sc + j)) * Dc + hh * DKc + lane];
  oacc[g][lane] = acc;
  __syncthreads();
  if (tid < DKc) {
    float r = (oacc[0][tid] + oacc[1][tid] + oacc[2][tid] + oacc[3][tid]) * inv;
    o[rowbase + tid] = r;
  }
}

// ---------------- host orchestration ----------------
extern "C" void kernel_launch(void* const* d_in, const int* in_sizes, int n_in,
                              void* d_out, int out_size, void* d_ws, size_t ws_size,
                              hipStream_t stream) {
  const float* emb  = (const float*)d_in[0];
  const float* Wq   = (const float*)d_in[1];
  const float* Wk   = (const float*)d_in[2];
  const float* Wv   = (const float*)d_in[3];
  const float* Wo   = (const float*)d_in[4];
  const float* ln1a = (const float*)d_in[5];
  const float* ln1b = (const float*)d_in[6];
  const float* ln2a = (const float*)d_in[7];
  const float* ln2b = (const float*)d_in[8];
  const float* W1   = (const float*)d_in[9];
  const float* b1   = (const float*)d_in[10];
  const float* W2   = (const float*)d_in[11];
  const float* b2   = (const float*)d_in[12];
  const float* fna  = (const float*)d_in[13];
  const float* fnb  = (const float*)d_in[14];
  const float* pb   = (const float*)d_in[15];
  const int*   x    = (const int*)d_in[16];
  float* out = (float*)d_out;

  // workspace layout (fp32): h, xn, q, k, v (T*D each) + f1 (T*F)  ~= 57 MB
  float* ws = (float*)d_ws;
  float* h  = ws;
  float* xn = h  + (size_t)Tc * Dc;
  float* q  = xn + (size_t)Tc * Dc;
  float* k  = q  + (size_t)Tc * Dc;
  float* v  = k  + (size_t)Tc * Dc;
  float* f1 = v  + (size_t)Tc * Dc;

  embed_kernel<<<Tc, 256, 0, stream>>>(emb, x, h);

  dim3 g64(Dc / 64, Tc / 64);      // (12, 32)
  dim3 gf1(Fc / 128, Tc / 128);    // (24, 16)
  for (int l = 0; l < Lc; ++l) {
    ln_kernel<<<Tc, 256, 0, stream>>>(h, ln1a + l * Dc, ln1b + l * Dc, xn);
    gemm_kernel<64, 64, false, false, false, false><<<g64, 256, 0, stream>>>(
        xn, Wq + (size_t)l * Dc * Dc, nullptr, nullptr, q, Tc, Dc, Dc);
    gemm_kernel<64, 64, false, false, false, false><<<g64, 256, 0, stream>>>(
        xn, Wk + (size_t)l * Dc * Dc, nullptr, nullptr, k, Tc, Dc, Dc);
    gemm_kernel<64, 64, false, false, false, false><<<g64, 256, 0, stream>>>(
        xn, Wv + (size_t)l * Dc * Dc, nullptr, nullptr, v, Tc, Dc, Dc);
    attn_kernel<<<Bc * Hc * Sc, 256, 0, stream>>>(q, k, v, xn);
    gemm_kernel<64, 64, false, false, false, true><<<g64, 256, 0, stream>>>(
        xn, Wo + (size_t)l * Dc * Dc, nullptr, h, h, Tc, Dc, Dc);
    ln_kernel<<<Tc, 256, 0, stream>>>(h, ln2a + l * Dc, ln2b + l * Dc, xn);
    gemm_kernel<128, 128, false, true, true, false><<<gf1, 256, 0, stream>>>(
        xn, W1 + (size_t)l * Dc * Fc, b1 + (size_t)l * Fc, nullptr, f1, Tc, Fc, Dc);
    gemm_kernel<64, 64, false, true, false, true><<<g64, 256, 0, stream>>>(
        f1, W2 + (size_t)l * Fc * Dc, b2 + (size_t)l * Dc, h, h, Tc, Dc, Fc);
  }
  ln_kernel<<<Tc, 256, 0, stream>>>(h, fna, fnb, xn);
  dim3 gl((Vc + 127) / 128, Tc / 128);  // (393, 16)
  gemm_kernel<128, 128, true, true, false, false><<<gl, 256, 0, stream>>>(
      xn, emb, pb, nullptr, out, Tc, Vc, Dc);
}

// Round 2
// 9724.667 us; speedup vs baseline: 1.7839x; 1.7839x over previous
//
#include <hip/hip_runtime.h>
#include <math.h>

// Problem constants
constexpr int Lc = 12, Bc = 2, Sc = 1024, Dc = 768, Hc = 12, Fc = 3072, Vc = 50257, DKc = 64;
constexpr int Tc = Bc * Sc;   // 2048 token rows
constexpr int QKVN = 3 * Dc;  // 2304
constexpr int Vpad = 50304;   // V padded to multiple of 128

typedef __attribute__((ext_vector_type(8))) __bf16 bf16x8;
typedef __attribute__((ext_vector_type(4))) float f32x4;

// ---------------- bf16 helpers (bit-level, RNE) ----------------
__device__ __forceinline__ unsigned short f2b(float f) {
  union { float f; unsigned int u; } v; v.f = f;
  unsigned int r = v.u + 0x7FFFu + ((v.u >> 16) & 1u);
  return (unsigned short)(r >> 16);
}
__device__ __forceinline__ float b2f(unsigned short u) {
  return __uint_as_float(((unsigned int)u) << 16);
}

// async global->LDS, 16B per lane. lds base must be wave-uniform; HW adds lane*16.
__device__ __forceinline__ void gload16(const void* g, void* l) {
  __builtin_amdgcn_global_load_lds((const __attribute__((address_space(1))) void*)g,
                                   (__attribute__((address_space(3))) void*)l, 16, 0, 0);
}

// ---------------- block reduction helpers (256 threads = 4 waves) ----------------
__device__ __forceinline__ float bred_sum(float v, volatile float* sb) {
#pragma unroll
  for (int o = 32; o; o >>= 1) v += __shfl_down(v, o);
  int w = threadIdx.x >> 6;
  __syncthreads();
  if ((threadIdx.x & 63) == 0) sb[w] = v;
  __syncthreads();
  return sb[0] + sb[1] + sb[2] + sb[3];
}
__device__ __forceinline__ float bred_max(float v, volatile float* sb) {
#pragma unroll
  for (int o = 32; o; o >>= 1) v = fmaxf(v, __shfl_down(v, o));
  int w = threadIdx.x >> 6;
  __syncthreads();
  if ((threadIdx.x & 63) == 0) sb[w] = v;
  __syncthreads();
  return fmaxf(fmaxf(sb[0], sb[1]), fmaxf(sb[2], sb[3]));
}

// ---------------- embedding + positional encoding (fp32 h) ----------------
__global__ __launch_bounds__(256) void embed_kernel(const float* __restrict__ emb,
                                                    const int* __restrict__ x,
                                                    float* __restrict__ h) {
  int t = blockIdx.x;
  int s = t & (Sc - 1);
  int tok = x[t];
  const float scale = 27.712812921102035f;  // sqrt(768)
  for (int d = threadIdx.x; d < Dc; d += 256) {
    int i = d >> 1;
    float div = __expf((float)(2 * i) * (-9.210340371976184f / (float)Dc));
    float ang = (float)s * div;
    float pe = (d & 1) ? cosf(ang) : sinf(ang);
    h[(size_t)t * Dc + d] = emb[(size_t)tok * Dc + d] * scale + pe;
  }
}

// ---------------- emb -> bf16 [Vpad][768], zero-padded ----------------
__global__ __launch_bounds__(256) void convert_emb_kernel(const float* __restrict__ emb,
                                                          ushort* __restrict__ embT) {
  const size_t total4 = (size_t)Vpad * Dc / 4;
  for (size_t i = (size_t)blockIdx.x * 256 + threadIdx.x; i < total4; i += (size_t)gridDim.x * 256) {
    size_t e = i * 4;
    int row = (int)(e / Dc);
    ushort4 w;
    if (row < Vc) {
      float4 f = *(const float4*)&emb[e];
      w.x = f2b(f.x); w.y = f2b(f.y); w.z = f2b(f.z); w.w = f2b(f.w);
    } else {
      w = make_ushort4(0, 0, 0, 0);
    }
    *(ushort4*)&embT[e] = w;
  }
}

// ---------------- per-layer weight transpose-convert: W[K,N] fp32 -> Wt[N,K] bf16 ----------------
// grid.x = 1728 blocks of 64x64 tiles: Wq,Wk,Wv (->WqkvT), Wo, W1, W2
__global__ __launch_bounds__(256) void transpose_layer_kernel(
    const float* __restrict__ Wq, const float* __restrict__ Wk, const float* __restrict__ Wv,
    const float* __restrict__ Wo, const float* __restrict__ W1, const float* __restrict__ W2,
    int l, ushort* __restrict__ WqkvT, ushort* __restrict__ WoT,
    ushort* __restrict__ W1T, ushort* __restrict__ W2T) {
  __shared__ float tile[64][65];
  int bid = blockIdx.x;
  const float* src; ushort* dst; int N, Kd, tt;
  if (bid < 432) {
    int m = bid / 144; tt = bid % 144;
    src = (m == 0 ? Wq : (m == 1 ? Wk : Wv)) + (size_t)l * Dc * Dc;
    N = Dc; Kd = Dc; dst = WqkvT + (size_t)m * Dc * Dc;
  } else if (bid < 576) {
    tt = bid - 432; src = Wo + (size_t)l * Dc * Dc; N = Dc; Kd = Dc; dst = WoT;
  } else if (bid < 1152) {
    tt = bid - 576; src = W1 + (size_t)l * Dc * Fc; N = Fc; Kd = Dc; dst = W1T;
  } else {
    tt = bid - 1152; src = W2 + (size_t)l * Fc * Dc; N = Dc; Kd = Fc; dst = W2T;
  }
  int nt = N / 64;
  int k0 = (tt / nt) * 64, n0 = (tt % nt) * 64;
  int t = threadIdx.x;
  int r0 = t >> 4, c4 = (t & 15) * 4;
#pragma unroll
  for (int rr = 0; rr < 4; ++rr) {
    int r = r0 + rr * 16;
    float4 f = *(const float4*)&src[(size_t)(k0 + r) * N + n0 + c4];
    tile[r][c4] = f.x; tile[r][c4 + 1] = f.y; tile[r][c4 + 2] = f.z; tile[r][c4 + 3] = f.w;
  }
  __syncthreads();
  int i0 = t >> 4, j4 = (t & 15) * 4;
#pragma unroll
  for (int rr = 0; rr < 4; ++rr) {
    int i = i0 + rr * 16;
    ushort4 w;
    w.x = f2b(tile[j4][i]); w.y = f2b(tile[j4 + 1][i]);
    w.z = f2b(tile[j4 + 2][i]); w.w = f2b(tile[j4 + 3][i]);
    *(ushort4*)&dst[(size_t)(n0 + i) * Kd + k0 + j4] = w;
  }
}

// ---------------- layernorm fp32-in -> bf16-out ----------------
__global__ __launch_bounds__(256) void ln_kernel(const float* __restrict__ in,
                                                 const float* __restrict__ ga,
                                                 const float* __restrict__ be,
                                                 ushort* __restrict__ out) {
  __shared__ float sb[4];
  int t = blockIdx.x;
  const float* row = in + (size_t)t * Dc;
  int tid = threadIdx.x;
  float x0 = row[tid], x1 = row[tid + 256], x2 = row[tid + 512];
  float s = bred_sum(x0 + x1 + x2, sb);
  float mean = s * (1.0f / 768.0f);
  float d0 = x0 - mean, d1 = x1 - mean, d2 = x2 - mean;
  float vs = bred_sum(d0 * d0 + d1 * d1 + d2 * d2, sb);
  float inv = 1.0f / (sqrtf(vs * (1.0f / 767.0f)) + 1e-6f);
  ushort* orow = out + (size_t)t * Dc;
  orow[tid] = f2b(ga[tid] * d0 * inv + be[tid]);
  orow[tid + 256] = f2b(ga[tid + 256] * d1 * inv + be[tid + 256]);
  orow[tid + 512] = f2b(ga[tid + 512] * d2 * inv + be[tid + 512]);
}

// ---------------- bf16 MFMA GEMM (m97 structure) ----------------
// C[M,N] = A[M,K] @ Bt[N,K]^T  (+bias, relu, +resid). 128x128 tile, BK=32, 4 waves.
// OT: ushort (bf16 out) or float.
template <typename OT, bool BIAS, bool RELU, bool RESID>
__global__ __launch_bounds__(256) void gemm_bf16(const ushort* __restrict__ A,
                                                 const ushort* __restrict__ Bt,
                                                 const float* __restrict__ bias,
                                                 const float* __restrict__ resid,
                                                 OT* __restrict__ C,
                                                 int M, int N, int K, int ldc) {
  __shared__ __attribute__((aligned(16))) ushort sm[8192];  // As[128*32] | Bs[128*32]
  ushort* As = sm;
  ushort* Bs = sm + 4096;
  const int tid = threadIdx.x;
  const int wid = tid >> 6, lane = tid & 63;
  const int wr = wid >> 1, wc = wid & 1;
  const int kg = lane >> 4, fr = lane & 15;
  const int bm = blockIdx.y * 128, bn = blockIdx.x * 128;

  f32x4 acc[4][4] = {};

  for (int k0 = 0; k0 < K; k0 += 32) {
    // stage A tile (128x32) and B tile (128x32): 512 chunks of 16B each
    const ushort* Ab = A + (size_t)bm * K + k0;
    const ushort* Bb = Bt + (size_t)bn * K + k0;
#pragma unroll
    for (int it = 0; it < 2; ++it) {
      int c = it * 256 + tid;
      int row = c >> 2, kc = (c & 3) * 8;
      gload16(Ab + (size_t)row * K + kc, &As[(it * 256 + wid * 64) * 8]);
    }
#pragma unroll
    for (int it = 0; it < 2; ++it) {
      int c = it * 256 + tid;
      int row = c >> 2, kc = (c & 3) * 8;
      gload16(Bb + (size_t)row * K + kc, &Bs[(it * 256 + wid * 64) * 8]);
    }
    __syncthreads();  // drains vmcnt + lgkmcnt, tile visible

    bf16x8 af[4], bfr[4];
#pragma unroll
    for (int i = 0; i < 4; ++i)
      af[i] = *(const bf16x8*)&As[(wr * 64 + i * 16 + fr) * 32 + kg * 8];
#pragma unroll
    for (int j = 0; j < 4; ++j)
      bfr[j] = *(const bf16x8*)&Bs[(wc * 64 + j * 16 + fr) * 32 + kg * 8];
#pragma unroll
    for (int i = 0; i < 4; ++i)
#pragma unroll
      for (int j = 0; j < 4; ++j)
        acc[i][j] = __builtin_amdgcn_mfma_f32_16x16x32_bf16(af[i], bfr[j], acc[i][j], 0, 0, 0);
    __syncthreads();  // before next stage overwrites
  }

  // epilogue: C/D layout col = lane&15, row = (lane>>4)*4 + r
  const int r0 = kg * 4;
#pragma unroll
  for (int i = 0; i < 4; ++i) {
    int mbase = bm + wr * 64 + i * 16 + r0;
#pragma unroll
    for (int j = 0; j < 4; ++j) {
      int n = bn + wc * 64 + j * 16 + fr;
      if (n < N) {
        float bv = BIAS ? bias[n] : 0.0f;
#pragma unroll
        for (int r = 0; r < 4; ++r) {
          float v = acc[i][j][r] + bv;
          if (RELU) v = fmaxf(v, 0.0f);
          size_t idx = (size_t)(mbase + r) * ldc + n;
          if (RESID) v += resid[idx];
          if constexpr (sizeof(OT) == 2) C[idx] = (OT)f2b(v);
          else C[idx] = (OT)v;
        }
      }
    }
  }
}

// ---------------- causal attention: one block per (b, h, q-row); bf16 qkv ----------------
__global__ __launch_bounds__(256) void attn_kernel(const ushort* __restrict__ qkv,
                                                   ushort* __restrict__ o) {
  int bid = blockIdx.x;
  int qi = bid & (Sc - 1);
  int hb = bid >> 10;
  int hh = hb % Hc;
  int b = hb / Hc;
  const int tid = threadIdx.x;

  __shared__ float qs[DKc];
  __shared__ float p[Sc];
  __shared__ float red[4];
  __shared__ float oacc[4][DKc];

  const size_t rowq = (size_t)(b * Sc + qi) * QKVN + hh * DKc;
  if (tid < DKc) qs[tid] = b2f(qkv[rowq + tid]) * 0.125f;  // fold 1/sqrt(64)
  __syncthreads();

  int nk = qi + 1;
  float pmax = -1e30f;
  for (int j = tid; j < nk; j += 256) {
    const ushort* kr = qkv + (size_t)(b * Sc + j) * QKVN + Dc + hh * DKc;
    float s = 0.f;
#pragma unroll
    for (int d = 0; d < DKc; d += 4) {
      ushort4 k4 = *(const ushort4*)&kr[d];
      s += qs[d] * b2f(k4.x) + qs[d + 1] * b2f(k4.y) + qs[d + 2] * b2f(k4.z) + qs[d + 3] * b2f(k4.w);
    }
    p[j] = s;
    pmax = fmaxf(pmax, s);
  }
  pmax = bred_max(pmax, red);
  float psum = 0.f;
  for (int j = tid; j < nk; j += 256) {
    float e = __expf(p[j] - pmax);
    p[j] = e;
    psum += e;
  }
  psum = bred_sum(psum, red);
  float inv = 1.0f / psum;

  int g = tid >> 6, lane = tid & 63;
  float acc = 0.f;
  for (int j = g; j < nk; j += 4)
    acc += p[j] * b2f(qkv[(size_t)(b * Sc + j) * QKVN + 2 * Dc + hh * DKc + lane]);
  oacc[g][lane] = acc;
  __syncthreads();
  if (tid < DKc) {
    float r = (oacc[0][tid] + oacc[1][tid] + oacc[2][tid] + oacc[3][tid]) * inv;
    o[(size_t)(b * Sc + qi) * Dc + hh * DKc + tid] = f2b(r);
  }
}

// ---------------- host orchestration ----------------
extern "C" void kernel_launch(void* const* d_in, const int* in_sizes, int n_in,
                              void* d_out, int out_size, void* d_ws, size_t ws_size,
                              hipStream_t stream) {
  const float* emb  = (const float*)d_in[0];
  const float* Wq   = (const float*)d_in[1];
  const float* Wk   = (const float*)d_in[2];
  const float* Wv   = (const float*)d_in[3];
  const float* Wo   = (const float*)d_in[4];
  const float* ln1a = (const float*)d_in[5];
  const float* ln1b = (const float*)d_in[6];
  const float* ln2a = (const float*)d_in[7];
  const float* ln2b = (const float*)d_in[8];
  const float* W1   = (const float*)d_in[9];
  const float* b1   = (const float*)d_in[10];
  const float* W2   = (const float*)d_in[11];
  const float* b2   = (const float*)d_in[12];
  const float* fna  = (const float*)d_in[13];
  const float* fnb  = (const float*)d_in[14];
  const float* pb   = (const float*)d_in[15];
  const int*   x    = (const int*)d_in[16];
  float* out = (float*)d_out;

  // workspace layout
  float* h = (float*)d_ws;                       // T*D fp32
  ushort* xn    = (ushort*)(h + (size_t)Tc * Dc);  // T*D
  ushort* qkv   = xn + (size_t)Tc * Dc;            // T*2304
  ushort* ao    = qkv + (size_t)Tc * QKVN;         // T*D
  ushort* f1    = ao + (size_t)Tc * Dc;            // T*F
  ushort* embT  = f1 + (size_t)Tc * Fc;            // Vpad*D
  ushort* WqkvT = embT + (size_t)Vpad * Dc;        // 2304*768
  ushort* WoT   = WqkvT + (size_t)QKVN * Dc;       // 768*768
  ushort* W1T   = WoT + (size_t)Dc * Dc;           // 3072*768
  ushort* W2T   = W1T + (size_t)Fc * Dc;           // 768*3072

  embed_kernel<<<Tc, 256, 0, stream>>>(emb, x, h);
  convert_emb_kernel<<<2048, 256, 0, stream>>>(emb, embT);

  dim3 gQKV(QKVN / 128, Tc / 128);  // (18,16)
  dim3 gD(Dc / 128, Tc / 128);      // (6,16)
  dim3 gF(Fc / 128, Tc / 128);      // (24,16)
  for (int l = 0; l < Lc; ++l) {
    transpose_layer_kernel<<<1728, 256, 0, stream>>>(Wq, Wk, Wv, Wo, W1, W2, l,
                                                     WqkvT, WoT, W1T, W2T);
    ln_kernel<<<Tc, 256, 0, stream>>>(h, ln1a + l * Dc, ln1b + l * Dc, xn);
    gemm_bf16<ushort, false, false, false><<<gQKV, 256, 0, stream>>>(
        xn, WqkvT, nullptr, nullptr, qkv, Tc, QKVN, Dc, QKVN);
    attn_kernel<<<Bc * Hc * Sc, 256, 0, stream>>>(qkv, ao);
    gemm_bf16<float, false, false, true><<<gD, 256, 0, stream>>>(
        ao, WoT, nullptr, h, h, Tc, Dc, Dc, Dc);
    ln_kernel<<<Tc, 256, 0, stream>>>(h, ln2a + l * Dc, ln2b + l * Dc, xn);
    gemm_bf16<ushort, true, true, false><<<gF, 256, 0, stream>>>(
        xn, W1T, b1 + (size_t)l * Fc, nullptr, f1, Tc, Fc, Dc, Fc);
    gemm_bf16<float, true, false, true><<<gD, 256, 0, stream>>>(
        f1, W2T, b2 + (size_t)l * Dc, h, h, Tc, Dc, Fc, Dc);
  }
  ln_kernel<<<Tc, 256, 0, stream>>>(h, fna, fnb, xn);
  dim3 gL(Vpad / 128, Tc / 128);  // (393,16)
  gemm_bf16<float, true, false, false><<<gL, 256, 0, stream>>>(
      xn, embT, pb, nullptr, out, Tc, Vc, Dc, Vc);
}

// Round 3
// 3378.576 us; speedup vs baseline: 5.1346x; 2.8783x over previous
//
#include <hip/hip_runtime.h>
#include <math.h>

// Problem constants
constexpr int Lc = 12, Bc = 2, Sc = 1024, Dc = 768, Hc = 12, Fc = 3072, Vc = 50257, DKc = 64;
constexpr int Tc = Bc * Sc;   // 2048 token rows
constexpr int QKVN = 3 * Dc;  // 2304
constexpr int Vpad = 50304;   // V padded to multiple of 128

typedef __attribute__((ext_vector_type(8))) __bf16 bf16x8;
typedef __attribute__((ext_vector_type(8))) unsigned short u16x8;
typedef __attribute__((ext_vector_type(4))) float f32x4;

// ---------------- bf16 helpers (bit-level, RNE) ----------------
__device__ __forceinline__ unsigned short f2b(float f) {
  union { float f; unsigned int u; } v; v.f = f;
  unsigned int r = v.u + 0x7FFFu + ((v.u >> 16) & 1u);
  return (unsigned short)(r >> 16);
}
__device__ __forceinline__ float b2f(unsigned short u) {
  return __uint_as_float(((unsigned int)u) << 16);
}

// async global->LDS, 16B per lane. lds base must be wave-uniform; HW adds lane*16.
__device__ __forceinline__ void gload16(const void* g, void* l) {
  __builtin_amdgcn_global_load_lds((const __attribute__((address_space(1))) void*)g,
                                   (__attribute__((address_space(3))) void*)l, 16, 0, 0);
}

// ---------------- block reduction helpers (256 threads = 4 waves) ----------------
__device__ __forceinline__ float bred_sum(float v, volatile float* sb) {
#pragma unroll
  for (int o = 32; o; o >>= 1) v += __shfl_down(v, o);
  int w = threadIdx.x >> 6;
  __syncthreads();
  if ((threadIdx.x & 63) == 0) sb[w] = v;
  __syncthreads();
  return sb[0] + sb[1] + sb[2] + sb[3];
}

// ---------------- embedding + positional encoding (fp32 h) ----------------
__global__ __launch_bounds__(256) void embed_kernel(const float* __restrict__ emb,
                                                    const int* __restrict__ x,
                                                    float* __restrict__ h) {
  int t = blockIdx.x;
  int s = t & (Sc - 1);
  int tok = x[t];
  const float scale = 27.712812921102035f;  // sqrt(768)
  for (int d = threadIdx.x; d < Dc; d += 256) {
    int i = d >> 1;
    float div = __expf((float)(2 * i) * (-9.210340371976184f / (float)Dc));
    float ang = (float)s * div;
    float pe = (d & 1) ? cosf(ang) : sinf(ang);
    h[(size_t)t * Dc + d] = emb[(size_t)tok * Dc + d] * scale + pe;
  }
}

// ---------------- emb -> bf16 [Vpad][768], zero-padded ----------------
__global__ __launch_bounds__(256) void convert_emb_kernel(const float* __restrict__ emb,
                                                          ushort* __restrict__ embT) {
  const size_t total4 = (size_t)Vpad * Dc / 4;
  for (size_t i = (size_t)blockIdx.x * 256 + threadIdx.x; i < total4; i += (size_t)gridDim.x * 256) {
    size_t e = i * 4;
    int row = (int)(e / Dc);
    ushort4 w;
    if (row < Vc) {
      float4 f = *(const float4*)&emb[e];
      w.x = f2b(f.x); w.y = f2b(f.y); w.z = f2b(f.z); w.w = f2b(f.w);
    } else {
      w = make_ushort4(0, 0, 0, 0);
    }
    *(ushort4*)&embT[e] = w;
  }
}

// ---------------- per-layer weight transpose-convert: W[K,N] fp32 -> Wt[N,K] bf16 ----------------
__global__ __launch_bounds__(256) void transpose_layer_kernel(
    const float* __restrict__ Wq, const float* __restrict__ Wk, const float* __restrict__ Wv,
    const float* __restrict__ Wo, const float* __restrict__ W1, const float* __restrict__ W2,
    int l, ushort* __restrict__ WqkvT, ushort* __restrict__ WoT,
    ushort* __restrict__ W1T, ushort* __restrict__ W2T) {
  __shared__ float tile[64][65];
  int bid = blockIdx.x;
  const float* src; ushort* dst; int N, Kd, tt;
  if (bid < 432) {
    int m = bid / 144; tt = bid % 144;
    src = (m == 0 ? Wq : (m == 1 ? Wk : Wv)) + (size_t)l * Dc * Dc;
    N = Dc; Kd = Dc; dst = WqkvT + (size_t)m * Dc * Dc;
  } else if (bid < 576) {
    tt = bid - 432; src = Wo + (size_t)l * Dc * Dc; N = Dc; Kd = Dc; dst = WoT;
  } else if (bid < 1152) {
    tt = bid - 576; src = W1 + (size_t)l * Dc * Fc; N = Fc; Kd = Dc; dst = W1T;
  } else {
    tt = bid - 1152; src = W2 + (size_t)l * Fc * Dc; N = Dc; Kd = Fc; dst = W2T;
  }
  int nt = N / 64;
  int k0 = (tt / nt) * 64, n0 = (tt % nt) * 64;
  int t = threadIdx.x;
  int r0 = t >> 4, c4 = (t & 15) * 4;
#pragma unroll
  for (int rr = 0; rr < 4; ++rr) {
    int r = r0 + rr * 16;
    float4 f = *(const float4*)&src[(size_t)(k0 + r) * N + n0 + c4];
    tile[r][c4] = f.x; tile[r][c4 + 1] = f.y; tile[r][c4 + 2] = f.z; tile[r][c4 + 3] = f.w;
  }
  __syncthreads();
  int i0 = t >> 4, j4 = (t & 15) * 4;
#pragma unroll
  for (int rr = 0; rr < 4; ++rr) {
    int i = i0 + rr * 16;
    ushort4 w;
    w.x = f2b(tile[j4][i]); w.y = f2b(tile[j4 + 1][i]);
    w.z = f2b(tile[j4 + 2][i]); w.w = f2b(tile[j4 + 3][i]);
    *(ushort4*)&dst[(size_t)(n0 + i) * Kd + k0 + j4] = w;
  }
}

// ---------------- layernorm fp32-in -> bf16-out ----------------
__global__ __launch_bounds__(256) void ln_kernel(const float* __restrict__ in,
                                                 const float* __restrict__ ga,
                                                 const float* __restrict__ be,
                                                 ushort* __restrict__ out) {
  __shared__ float sb[4];
  int t = blockIdx.x;
  const float* row = in + (size_t)t * Dc;
  int tid = threadIdx.x;
  float x0 = row[tid], x1 = row[tid + 256], x2 = row[tid + 512];
  float s = bred_sum(x0 + x1 + x2, sb);
  float mean = s * (1.0f / 768.0f);
  float d0 = x0 - mean, d1 = x1 - mean, d2 = x2 - mean;
  float vs = bred_sum(d0 * d0 + d1 * d1 + d2 * d2, sb);
  float inv = 1.0f / (sqrtf(vs * (1.0f / 767.0f)) + 1e-6f);
  ushort* orow = out + (size_t)t * Dc;
  orow[tid] = f2b(ga[tid] * d0 * inv + be[tid]);
  orow[tid + 256] = f2b(ga[tid + 256] * d1 * inv + be[tid + 256]);
  orow[tid + 512] = f2b(ga[tid + 512] * d2 * inv + be[tid + 512]);
}

// ---------------- bf16 MFMA GEMM (m97 structure) ----------------
template <typename OT, bool BIAS, bool RELU, bool RESID>
__global__ __launch_bounds__(256) void gemm_bf16(const ushort* __restrict__ A,
                                                 const ushort* __restrict__ Bt,
                                                 const float* __restrict__ bias,
                                                 const float* __restrict__ resid,
                                                 OT* __restrict__ C,
                                                 int M, int N, int K, int ldc) {
  __shared__ __attribute__((aligned(16))) ushort sm[8192];  // As[128*32] | Bs[128*32]
  ushort* As = sm;
  ushort* Bs = sm + 4096;
  const int tid = threadIdx.x;
  const int wid = tid >> 6, lane = tid & 63;
  const int wr = wid >> 1, wc = wid & 1;
  const int kg = lane >> 4, fr = lane & 15;
  const int bm = blockIdx.y * 128, bn = blockIdx.x * 128;

  f32x4 acc[4][4] = {};

  for (int k0 = 0; k0 < K; k0 += 32) {
    const ushort* Ab = A + (size_t)bm * K + k0;
    const ushort* Bb = Bt + (size_t)bn * K + k0;
#pragma unroll
    for (int it = 0; it < 2; ++it) {
      int c = it * 256 + tid;
      int row = c >> 2, kc = (c & 3) * 8;
      gload16(Ab + (size_t)row * K + kc, &As[(it * 256 + wid * 64) * 8]);
    }
#pragma unroll
    for (int it = 0; it < 2; ++it) {
      int c = it * 256 + tid;
      int row = c >> 2, kc = (c & 3) * 8;
      gload16(Bb + (size_t)row * K + kc, &Bs[(it * 256 + wid * 64) * 8]);
    }
    __syncthreads();

    bf16x8 af[4], bfr[4];
#pragma unroll
    for (int i = 0; i < 4; ++i)
      af[i] = *(const bf16x8*)&As[(wr * 64 + i * 16 + fr) * 32 + kg * 8];
#pragma unroll
    for (int j = 0; j < 4; ++j)
      bfr[j] = *(const bf16x8*)&Bs[(wc * 64 + j * 16 + fr) * 32 + kg * 8];
#pragma unroll
    for (int i = 0; i < 4; ++i)
#pragma unroll
      for (int j = 0; j < 4; ++j)
        acc[i][j] = __builtin_amdgcn_mfma_f32_16x16x32_bf16(af[i], bfr[j], acc[i][j], 0, 0, 0);
    __syncthreads();
  }

  const int r0 = kg * 4;
#pragma unroll
  for (int i = 0; i < 4; ++i) {
    int mbase = bm + wr * 64 + i * 16 + r0;
#pragma unroll
    for (int j = 0; j < 4; ++j) {
      int n = bn + wc * 64 + j * 16 + fr;
      if (n < N) {
        float bv = BIAS ? bias[n] : 0.0f;
#pragma unroll
        for (int r = 0; r < 4; ++r) {
          float v = acc[i][j][r] + bv;
          if (RELU) v = fmaxf(v, 0.0f);
          size_t idx = (size_t)(mbase + r) * ldc + n;
          if (RESID) v += resid[idx];
          if constexpr (sizeof(OT) == 2) C[idx] = (OT)f2b(v);
          else C[idx] = (OT)v;
        }
      }
    }
  }
}

// ---------------- flash attention: block = 64 q-rows of one (b,h); 4 waves x 16 rows ----------------
// qkv: [T][2304] bf16 (Q|K|V). o: [T][768] bf16.
__global__ __launch_bounds__(256) void flash_attn_kernel(const ushort* __restrict__ qkv,
                                                         ushort* __restrict__ o) {
  const int qt = blockIdx.x;            // q-tile 0..15
  const int hb = blockIdx.y;            // b*H + h
  const int hh = hb % Hc, b = hb / Hc;
  const int tid = threadIdx.x;
  const int w = tid >> 6, lane = tid & 63;
  const int g = lane >> 4, c = lane & 15;

  // K row-major [64 kv][64 dk], V^T [64 d][64 kv], P per-wave [16 q][64 kv] — all XOR-swizzled
  __shared__ __attribute__((aligned(16))) ushort Ks[64 * 64];
  __shared__ __attribute__((aligned(16))) ushort Vt[64 * 64];
  __shared__ __attribute__((aligned(16))) ushort Ps[4][16 * 64];

  const int q0 = qt * 64;
  const int qw = q0 + w * 16;           // wave's q base

  // Q fragment (A operand): lane holds Q[qw + c][kk*32 + g*8 .. +8]
  bf16x8 aq[2];
  {
    const size_t qrow = (size_t)(b * Sc + qw + c) * QKVN + hh * DKc;
#pragma unroll
    for (int kk = 0; kk < 2; ++kk)
      aq[kk] = *(const bf16x8*)&qkv[qrow + kk * 32 + g * 8];
  }

  float m_r[4], l_r[4];
  f32x4 oa[4] = {};
#pragma unroll
  for (int r = 0; r < 4; ++r) { m_r[r] = -1e30f; l_r[r] = 0.f; }

  const int ntiles = qt + 1;
  for (int t = 0; t < ntiles; ++t) {
    const int kv0 = t * 64;
    // ---- stage K tile (swizzled row-major)
#pragma unroll
    for (int it = 0; it < 2; ++it) {
      int idx = it * 256 + tid;         // 0..511 chunks of 8 elems
      int kv = idx >> 3, ck = idx & 7;
      u16x8 kd = *(const u16x8*)&qkv[(size_t)(b * Sc + kv0 + kv) * QKVN + Dc + hh * DKc + ck * 8];
      *(u16x8*)((char*)Ks + ((kv * 128 + ck * 16) ^ ((kv & 7) << 4))) = kd;
    }
    // ---- stage V^T tile (swizzled by d-row)
    {
      int kv = tid >> 2;
      int dbase = (tid & 3) * 16;
      const ushort* vrow = &qkv[(size_t)(b * Sc + kv0 + kv) * QKVN + 2 * Dc + hh * DKc + dbase];
      u16x8 v0 = *(const u16x8*)&vrow[0];
      u16x8 v1 = *(const u16x8*)&vrow[8];
#pragma unroll
      for (int dd = 0; dd < 8; ++dd) {
        int d0 = dbase + dd, d1 = dbase + 8 + dd;
        *(ushort*)((char*)Vt + ((d0 * 128 + kv * 2) ^ ((d0 & 7) << 4))) = v0[dd];
        *(ushort*)((char*)Vt + ((d1 * 128 + kv * 2) ^ ((d1 & 7) << 4))) = v1[dd];
      }
    }
    __syncthreads();

    // ---- QK^T: S[16q x 64kv] per wave
    f32x4 sacc[4] = {};
#pragma unroll
    for (int jn = 0; jn < 4; ++jn) {
      int kvl = jn * 16 + c;
#pragma unroll
      for (int kk = 0; kk < 2; ++kk) {
        bf16x8 bk = *(const bf16x8*)((char*)Ks + ((kvl * 128 + kk * 64 + g * 16) ^ ((kvl & 7) << 4)));
        sacc[jn] = __builtin_amdgcn_mfma_f32_16x16x32_bf16(aq[kk], bk, sacc[jn], 0, 0, 0);
      }
    }

    // ---- scale + causal mask + online softmax
    const bool last = (t == ntiles - 1);
    float p[4][4];  // [jn][r]
#pragma unroll
    for (int jn = 0; jn < 4; ++jn) {
      int kvg = kv0 + jn * 16 + c;
#pragma unroll
      for (int r = 0; r < 4; ++r) {
        float s = sacc[jn][r] * 0.125f;
        if (last && kvg > qw + g * 4 + r) s = -1e30f;
        p[jn][r] = s;
      }
    }
#pragma unroll
    for (int r = 0; r < 4; ++r) {
      float mx = fmaxf(fmaxf(p[0][r], p[1][r]), fmaxf(p[2][r], p[3][r]));
#pragma unroll
      for (int off = 1; off < 16; off <<= 1) mx = fmaxf(mx, __shfl_xor(mx, off));
      float mnew = fmaxf(m_r[r], mx);
      float sf = __expf(m_r[r] - mnew);
      m_r[r] = mnew;
      float rs = 0.f;
#pragma unroll
      for (int jn = 0; jn < 4; ++jn) {
        float e = __expf(p[jn][r] - mnew);
        p[jn][r] = e;
        rs += e;
      }
#pragma unroll
      for (int off = 1; off < 16; off <<= 1) rs += __shfl_xor(rs, off);
      l_r[r] = l_r[r] * sf + rs;
#pragma unroll
      for (int jd = 0; jd < 4; ++jd) oa[jd][r] *= sf;
    }

    // ---- P -> bf16 -> per-wave LDS (swizzled); wave-local, no barrier needed
    {
      ushort* pw = Ps[w];
#pragma unroll
      for (int jn = 0; jn < 4; ++jn)
#pragma unroll
        for (int r = 0; r < 4; ++r) {
          int row = g * 4 + r, col = jn * 16 + c;
          *(ushort*)((char*)pw + ((row * 128 + col * 2) ^ ((row & 7) << 4))) = f2b(p[jn][r]);
        }
      // ---- PV: O[16q x 64d] += P @ V
      bf16x8 ap[2];
#pragma unroll
      for (int kk = 0; kk < 2; ++kk)
        ap[kk] = *(const bf16x8*)((char*)pw + ((c * 128 + kk * 64 + g * 16) ^ ((c & 7) << 4)));
#pragma unroll
      for (int jd = 0; jd < 4; ++jd) {
        int d = jd * 16 + c;
#pragma unroll
        for (int kk = 0; kk < 2; ++kk) {
          bf16x8 bv = *(const bf16x8*)((char*)Vt + ((d * 128 + kk * 64 + g * 16) ^ ((d & 7) << 4)));
          oa[jd] = __builtin_amdgcn_mfma_f32_16x16x32_bf16(ap[kk], bv, oa[jd], 0, 0, 0);
        }
      }
    }
    __syncthreads();  // protect Ks/Vt before next tile staging
  }

  // ---- epilogue: normalize and store
#pragma unroll
  for (int r = 0; r < 4; ++r) {
    int q = qw + g * 4 + r;
    float inv = 1.0f / l_r[r];
    size_t base = (size_t)(b * Sc + q) * Dc + hh * DKc;
#pragma unroll
    for (int jd = 0; jd < 4; ++jd)
      o[base + jd * 16 + c] = f2b(oa[jd][r] * inv);
  }
}

// ---------------- host orchestration ----------------
extern "C" void kernel_launch(void* const* d_in, const int* in_sizes, int n_in,
                              void* d_out, int out_size, void* d_ws, size_t ws_size,
                              hipStream_t stream) {
  const float* emb  = (const float*)d_in[0];
  const float* Wq   = (const float*)d_in[1];
  const float* Wk   = (const float*)d_in[2];
  const float* Wv   = (const float*)d_in[3];
  const float* Wo   = (const float*)d_in[4];
  const float* ln1a = (const float*)d_in[5];
  const float* ln1b = (const float*)d_in[6];
  const float* ln2a = (const float*)d_in[7];
  const float* ln2b = (const float*)d_in[8];
  const float* W1   = (const float*)d_in[9];
  const float* b1   = (const float*)d_in[10];
  const float* W2   = (const float*)d_in[11];
  const float* b2   = (const float*)d_in[12];
  const float* fna  = (const float*)d_in[13];
  const float* fnb  = (const float*)d_in[14];
  const float* pb   = (const float*)d_in[15];
  const int*   x    = (const int*)d_in[16];
  float* out = (float*)d_out;

  // workspace layout
  float* h = (float*)d_ws;                         // T*D fp32
  ushort* xn    = (ushort*)(h + (size_t)Tc * Dc);  // T*D
  ushort* qkv   = xn + (size_t)Tc * Dc;            // T*2304
  ushort* ao    = qkv + (size_t)Tc * QKVN;         // T*D
  ushort* f1    = ao + (size_t)Tc * Dc;            // T*F
  ushort* embT  = f1 + (size_t)Tc * Fc;            // Vpad*D
  ushort* WqkvT = embT + (size_t)Vpad * Dc;        // 2304*768
  ushort* WoT   = WqkvT + (size_t)QKVN * Dc;       // 768*768
  ushort* W1T   = WoT + (size_t)Dc * Dc;           // 3072*768
  ushort* W2T   = W1T + (size_t)Fc * Dc;           // 768*3072

  embed_kernel<<<Tc, 256, 0, stream>>>(emb, x, h);
  convert_emb_kernel<<<2048, 256, 0, stream>>>(emb, embT);

  dim3 gQKV(QKVN / 128, Tc / 128);  // (18,16)
  dim3 gD(Dc / 128, Tc / 128);      // (6,16)
  dim3 gF(Fc / 128, Tc / 128);      // (24,16)
  dim3 gA(Sc / 64, Bc * Hc);        // (16,24)
  for (int l = 0; l < Lc; ++l) {
    transpose_layer_kernel<<<1728, 256, 0, stream>>>(Wq, Wk, Wv, Wo, W1, W2, l,
                                                     WqkvT, WoT, W1T, W2T);
    ln_kernel<<<Tc, 256, 0, stream>>>(h, ln1a + l * Dc, ln1b + l * Dc, xn);
    gemm_bf16<ushort, false, false, false><<<gQKV, 256, 0, stream>>>(
        xn, WqkvT, nullptr, nullptr, qkv, Tc, QKVN, Dc, QKVN);
    flash_attn_kernel<<<gA, 256, 0, stream>>>(qkv, ao);
    gemm_bf16<float, false, false, true><<<gD, 256, 0, stream>>>(
        ao, WoT, nullptr, h, h, Tc, Dc, Dc, Dc);
    ln_kernel<<<Tc, 256, 0, stream>>>(h, ln2a + l * Dc, ln2b + l * Dc, xn);
    gemm_bf16<ushort, true, true, false><<<gF, 256, 0, stream>>>(
        xn, W1T, b1 + (size_t)l * Fc, nullptr, f1, Tc, Fc, Dc, Fc);
    gemm_bf16<float, true, false, true><<<gD, 256, 0, stream>>>(
        f1, W2T, b2 + (size_t)l * Dc, h, h, Tc, Dc, Fc, Dc);
  }
  ln_kernel<<<Tc, 256, 0, stream>>>(h, fna, fnb, xn);
  dim3 gL(Vpad / 128, Tc / 128);  // (393,16)
  gemm_bf16<float, true, false, false><<<gL, 256, 0, stream>>>(
      xn, embT, pb, nullptr, out, Tc, Vc, Dc, Vc);
}

// Round 6
// 3009.756 us; speedup vs baseline: 5.7638x; 1.1225x over previous
//
#include <hip/hip_runtime.h>
#include <math.h>

// Problem constants
constexpr int Lc = 12, Bc = 2, Sc = 1024, Dc = 768, Hc = 12, Fc = 3072, Vc = 50257, DKc = 64;
constexpr int Tc = Bc * Sc;   // 2048 token rows
constexpr int QKVN = 3 * Dc;  // 2304
constexpr int Vpad = 50304;   // V padded to multiple of 128

typedef __attribute__((ext_vector_type(8))) __bf16 bf16x8;
typedef __attribute__((ext_vector_type(8))) unsigned short u16x8;
typedef __attribute__((ext_vector_type(4))) float f32x4;

// ---------------- bf16 helpers (bit-level, RNE) ----------------
__device__ __forceinline__ unsigned short f2b(float f) {
  union { float f; unsigned int u; } v; v.f = f;
  unsigned int r = v.u + 0x7FFFu + ((v.u >> 16) & 1u);
  return (unsigned short)(r >> 16);
}
__device__ __forceinline__ float b2f(unsigned short u) {
  return __uint_as_float(((unsigned int)u) << 16);
}

// async global->LDS, 16B per lane. lds base must be wave-uniform; HW adds lane*16.
__device__ __forceinline__ void gload16(const void* g, void* l) {
  __builtin_amdgcn_global_load_lds((const __attribute__((address_space(1))) void*)g,
                                   (__attribute__((address_space(3))) void*)l, 16, 0, 0);
}

// ---------------- block reduction helpers (256 threads = 4 waves) ----------------
__device__ __forceinline__ float bred_sum(float v, volatile float* sb) {
#pragma unroll
  for (int o = 32; o; o >>= 1) v += __shfl_down(v, o);
  int w = threadIdx.x >> 6;
  __syncthreads();
  if ((threadIdx.x & 63) == 0) sb[w] = v;
  __syncthreads();
  return sb[0] + sb[1] + sb[2] + sb[3];
}

// ---------------- embedding + positional encoding (fp32 h) ----------------
__global__ __launch_bounds__(256) void embed_kernel(const float* __restrict__ emb,
                                                    const int* __restrict__ x,
                                                    float* __restrict__ h) {
  int t = blockIdx.x;
  int s = t & (Sc - 1);
  int tok = x[t];
  const float scale = 27.712812921102035f;  // sqrt(768)
  for (int d = threadIdx.x; d < Dc; d += 256) {
    int i = d >> 1;
    float div = __expf((float)(2 * i) * (-9.210340371976184f / (float)Dc));
    float ang = (float)s * div;
    float pe = (d & 1) ? cosf(ang) : sinf(ang);
    h[(size_t)t * Dc + d] = emb[(size_t)tok * Dc + d] * scale + pe;
  }
}

// ---------------- emb -> bf16 [Vpad][768], zero-padded ----------------
__global__ __launch_bounds__(256) void convert_emb_kernel(const float* __restrict__ emb,
                                                          ushort* __restrict__ embT) {
  const size_t total4 = (size_t)Vpad * Dc / 4;
  for (size_t i = (size_t)blockIdx.x * 256 + threadIdx.x; i < total4; i += (size_t)gridDim.x * 256) {
    size_t e = i * 4;
    int row = (int)(e / Dc);
    ushort4 w;
    if (row < Vc) {
      float4 f = *(const float4*)&emb[e];
      w.x = f2b(f.x); w.y = f2b(f.y); w.z = f2b(f.z); w.w = f2b(f.w);
    } else {
      w = make_ushort4(0, 0, 0, 0);
    }
    *(ushort4*)&embT[e] = w;
  }
}

// ---------------- per-layer weight transpose-convert: W[K,N] fp32 -> Wt[N,K] bf16 ----------------
__global__ __launch_bounds__(256) void transpose_layer_kernel(
    const float* __restrict__ Wq, const float* __restrict__ Wk, const float* __restrict__ Wv,
    const float* __restrict__ Wo, const float* __restrict__ W1, const float* __restrict__ W2,
    int l, ushort* __restrict__ WqkvT, ushort* __restrict__ WoT,
    ushort* __restrict__ W1T, ushort* __restrict__ W2T) {
  __shared__ float tile[64][65];
  int bid = blockIdx.x;
  const float* src; ushort* dst; int N, Kd, tt;
  if (bid < 432) {
    int m = bid / 144; tt = bid % 144;
    src = (m == 0 ? Wq : (m == 1 ? Wk : Wv)) + (size_t)l * Dc * Dc;
    N = Dc; Kd = Dc; dst = WqkvT + (size_t)m * Dc * Dc;
  } else if (bid < 576) {
    tt = bid - 432; src = Wo + (size_t)l * Dc * Dc; N = Dc; Kd = Dc; dst = WoT;
  } else if (bid < 1152) {
    tt = bid - 576; src = W1 + (size_t)l * Dc * Fc; N = Fc; Kd = Dc; dst = W1T;
  } else {
    tt = bid - 1152; src = W2 + (size_t)l * Fc * Dc; N = Dc; Kd = Fc; dst = W2T;
  }
  int nt = N / 64;
  int k0 = (tt / nt) * 64, n0 = (tt % nt) * 64;
  int t = threadIdx.x;
  int r0 = t >> 4, c4 = (t & 15) * 4;
#pragma unroll
  for (int rr = 0; rr < 4; ++rr) {
    int r = r0 + rr * 16;
    float4 f = *(const float4*)&src[(size_t)(k0 + r) * N + n0 + c4];
    tile[r][c4] = f.x; tile[r][c4 + 1] = f.y; tile[r][c4 + 2] = f.z; tile[r][c4 + 3] = f.w;
  }
  __syncthreads();
  int i0 = t >> 4, j4 = (t & 15) * 4;
#pragma unroll
  for (int rr = 0; rr < 4; ++rr) {
    int i = i0 + rr * 16;
    ushort4 w;
    w.x = f2b(tile[j4][i]); w.y = f2b(tile[j4 + 1][i]);
    w.z = f2b(tile[j4 + 2][i]); w.w = f2b(tile[j4 + 3][i]);
    *(ushort4*)&dst[(size_t)(n0 + i) * Kd + k0 + j4] = w;
  }
}

// ---------------- layernorm fp32-in -> bf16-out ----------------
__global__ __launch_bounds__(256) void ln_kernel(const float* __restrict__ in,
                                                 const float* __restrict__ ga,
                                                 const float* __restrict__ be,
                                                 ushort* __restrict__ out) {
  __shared__ float sb[4];
  int t = blockIdx.x;
  const float* row = in + (size_t)t * Dc;
  int tid = threadIdx.x;
  float x0 = row[tid], x1 = row[tid + 256], x2 = row[tid + 512];
  float s = bred_sum(x0 + x1 + x2, sb);
  float mean = s * (1.0f / 768.0f);
  float d0 = x0 - mean, d1 = x1 - mean, d2 = x2 - mean;
  float vs = bred_sum(d0 * d0 + d1 * d1 + d2 * d2, sb);
  float inv = 1.0f / (sqrtf(vs * (1.0f / 767.0f)) + 1e-6f);
  ushort* orow = out + (size_t)t * Dc;
  orow[tid] = f2b(ga[tid] * d0 * inv + be[tid]);
  orow[tid + 256] = f2b(ga[tid + 256] * d1 * inv + be[tid + 256]);
  orow[tid + 512] = f2b(ga[tid + 512] * d2 * inv + be[tid + 512]);
}

// ---------------- bf16 MFMA GEMM (m97 structure, BM in {64,128}) ----------------
// C[M,N] = A[M,K] @ Bt[N,K]^T (+bias, relu, +resid).  BN=128 fixed, BK=32, 4 waves.
// SWAP: blockIdx.x = M-tile (fastest) for B-panel L2/L3 reuse (logits GEMM).
template <typename OT, int BM, bool BIAS, bool RELU, bool RESID, bool SWAP>
__global__ __launch_bounds__(256) void gemm_bf16(const ushort* __restrict__ A,
                                                 const ushort* __restrict__ Bt,
                                                 const float* __restrict__ bias,
                                                 const float* __restrict__ resid,
                                                 OT* __restrict__ C,
                                                 int M, int N, int K, int ldc) {
  constexpr int MW = BM / 64;          // m-wave count (1 or 2)
  constexpr int NW = 4 / MW;           // n-wave count (4 or 2)
  constexpr int WCOLS = 128 / NW;      // cols per wave (32 or 64)
  constexpr int NJ = WCOLS / 16;       // n-frags per wave (2 or 4)
  __shared__ __attribute__((aligned(16))) ushort sm[(BM + 128) * 32];
  ushort* As = sm;                     // [BM][32]
  ushort* Bs = sm + BM * 32;           // [128][32]
  const int tid = threadIdx.x;
  const int wid = tid >> 6, lane = tid & 63;
  const int wr = (MW == 2) ? (wid >> 1) : 0;
  const int wc = (MW == 2) ? (wid & 1) : wid;
  const int kg = lane >> 4, fr = lane & 15;
  const int bm = (SWAP ? blockIdx.x : blockIdx.y) * BM;
  const int bn = (SWAP ? blockIdx.y : blockIdx.x) * 128;

  f32x4 acc[4][NJ] = {};

  for (int k0 = 0; k0 < K; k0 += 32) {
    const ushort* Ab = A + (size_t)bm * K + k0;
    const ushort* Bb = Bt + (size_t)bn * K + k0;
#pragma unroll
    for (int it = 0; it < BM / 64; ++it) {
      int c = it * 256 + tid;
      int row = c >> 2, kc = (c & 3) * 8;
      gload16(Ab + (size_t)row * K + kc, &As[(it * 256 + wid * 64) * 8]);
    }
#pragma unroll
    for (int it = 0; it < 2; ++it) {
      int c = it * 256 + tid;
      int row = c >> 2, kc = (c & 3) * 8;
      gload16(Bb + (size_t)row * K + kc, &Bs[(it * 256 + wid * 64) * 8]);
    }
    __syncthreads();

    bf16x8 af[4], bfr[NJ];
#pragma unroll
    for (int i = 0; i < 4; ++i)
      af[i] = *(const bf16x8*)&As[(wr * 64 + i * 16 + fr) * 32 + kg * 8];
#pragma unroll
    for (int j = 0; j < NJ; ++j)
      bfr[j] = *(const bf16x8*)&Bs[(wc * WCOLS + j * 16 + fr) * 32 + kg * 8];
#pragma unroll
    for (int i = 0; i < 4; ++i)
#pragma unroll
      for (int j = 0; j < NJ; ++j)
        acc[i][j] = __builtin_amdgcn_mfma_f32_16x16x32_bf16(af[i], bfr[j], acc[i][j], 0, 0, 0);
    __syncthreads();
  }

  const int r0 = kg * 4;
#pragma unroll
  for (int i = 0; i < 4; ++i) {
    int mbase = bm + wr * 64 + i * 16 + r0;
#pragma unroll
    for (int j = 0; j < NJ; ++j) {
      int n = bn + wc * WCOLS + j * 16 + fr;
      if (n < N) {
        float bv = BIAS ? bias[n] : 0.0f;
#pragma unroll
        for (int r = 0; r < 4; ++r) {
          float v = acc[i][j][r] + bv;
          if (RELU) v = fmaxf(v, 0.0f);
          size_t idx = (size_t)(mbase + r) * ldc + n;
          if (RESID) v += resid[idx];
          if constexpr (sizeof(OT) == 2) C[idx] = (OT)f2b(v);
          else C[idx] = (OT)v;
        }
      }
    }
  }
}

// ---------------- flash attention: block = 64 q-rows of one (b,h); 4 waves x 16 rows ----------------
// qkv: [T][2304] bf16 (Q|K|V). o: [T][768] bf16.
__global__ __launch_bounds__(256) void flash_attn_kernel(const ushort* __restrict__ qkv,
                                                         ushort* __restrict__ o) {
  const int qt = gridDim.x - 1 - blockIdx.x;  // long blocks dispatch first
  const int hb = blockIdx.y;                  // b*H + h
  const int hh = hb % Hc, b = hb / Hc;
  const int tid = threadIdx.x;
  const int w = tid >> 6, lane = tid & 63;
  const int g = lane >> 4, c = lane & 15;

  __shared__ __attribute__((aligned(16))) ushort Ks[64 * 64];
  __shared__ __attribute__((aligned(16))) ushort Vt[64 * 64];
  __shared__ __attribute__((aligned(16))) ushort Ps[4][16 * 64];

  const int q0 = qt * 64;
  const int qw = q0 + w * 16;

  bf16x8 aq[2];
  {
    const size_t qrow = (size_t)(b * Sc + qw + c) * QKVN + hh * DKc;
#pragma unroll
    for (int kk = 0; kk < 2; ++kk)
      aq[kk] = *(const bf16x8*)&qkv[qrow + kk * 32 + g * 8];
  }

  float m_r[4], l_r[4];
  f32x4 oa[4] = {};
#pragma unroll
  for (int r = 0; r < 4; ++r) { m_r[r] = -1e30f; l_r[r] = 0.f; }

  const int ntiles = qt + 1;
  for (int t = 0; t < ntiles; ++t) {
    const int kv0 = t * 64;
#pragma unroll
    for (int it = 0; it < 2; ++it) {
      int idx = it * 256 + tid;
      int kv = idx >> 3, ck = idx & 7;
      u16x8 kd = *(const u16x8*)&qkv[(size_t)(b * Sc + kv0 + kv) * QKVN + Dc + hh * DKc + ck * 8];
      *(u16x8*)((char*)Ks + ((kv * 128 + ck * 16) ^ ((kv & 7) << 4))) = kd;
    }
    {
      int kv = tid >> 2;
      int dbase = (tid & 3) * 16;
      const ushort* vrow = &qkv[(size_t)(b * Sc + kv0 + kv) * QKVN + 2 * Dc + hh * DKc + dbase];
      u16x8 v0 = *(const u16x8*)&vrow[0];
      u16x8 v1 = *(const u16x8*)&vrow[8];
#pragma unroll
      for (int dd = 0; dd < 8; ++dd) {
        int d0 = dbase + dd, d1 = dbase + 8 + dd;
        *(ushort*)((char*)Vt + ((d0 * 128 + kv * 2) ^ ((d0 & 7) << 4))) = v0[dd];
        *(ushort*)((char*)Vt + ((d1 * 128 + kv * 2) ^ ((d1 & 7) << 4))) = v1[dd];
      }
    }
    __syncthreads();

    // ---- QK^T
    f32x4 sacc[4] = {};
#pragma unroll
    for (int jn = 0; jn < 4; ++jn) {
      int kvl = jn * 16 + c;
#pragma unroll
      for (int kk = 0; kk < 2; ++kk) {
        bf16x8 bk = *(const bf16x8*)((char*)Ks + ((kvl * 128 + kk * 64 + g * 16) ^ ((kvl & 7) << 4)));
        sacc[jn] = __builtin_amdgcn_mfma_f32_16x16x32_bf16(aq[kk], bk, sacc[jn], 0, 0, 0);
      }
    }

    // ---- scale + causal mask + online softmax
    const bool last = (t == ntiles - 1);
    float p[4][4];
#pragma unroll
    for (int jn = 0; jn < 4; ++jn) {
      int kvg = kv0 + jn * 16 + c;
#pragma unroll
      for (int r = 0; r < 4; ++r) {
        float s = sacc[jn][r] * 0.125f;
        if (last && kvg > qw + g * 4 + r) s = -1e30f;
        p[jn][r] = s;
      }
    }
#pragma unroll
    for (int r = 0; r < 4; ++r) {
      float mx = fmaxf(fmaxf(p[0][r], p[1][r]), fmaxf(p[2][r], p[3][r]));
#pragma unroll
      for (int off = 1; off < 16; off <<= 1) mx = fmaxf(mx, __shfl_xor(mx, off));
      float mnew = fmaxf(m_r[r], mx);
      float sf = __expf(m_r[r] - mnew);
      m_r[r] = mnew;
      float rs = 0.f;
#pragma unroll
      for (int jn = 0; jn < 4; ++jn) {
        float e = __expf(p[jn][r] - mnew);
        p[jn][r] = e;
        rs += e;
      }
#pragma unroll
      for (int off = 1; off < 16; off <<= 1) rs += __shfl_xor(rs, off);
      l_r[r] = l_r[r] * sf + rs;
#pragma unroll
      for (int jd = 0; jd < 4; ++jd) oa[jd][r] *= sf;
    }

    // ---- P -> bf16 -> per-wave LDS (swizzled); wave-local
    {
      ushort* pw = Ps[w];
#pragma unroll
      for (int jn = 0; jn < 4; ++jn)
#pragma unroll
        for (int r = 0; r < 4; ++r) {
          int row = g * 4 + r, col = jn * 16 + c;
          *(ushort*)((char*)pw + ((row * 128 + col * 2) ^ ((row & 7) << 4))) = f2b(p[jn][r]);
        }
      bf16x8 ap[2];
#pragma unroll
      for (int kk = 0; kk < 2; ++kk)
        ap[kk] = *(const bf16x8*)((char*)pw + ((c * 128 + kk * 64 + g * 16) ^ ((c & 7) << 4)));
#pragma unroll
      for (int jd = 0; jd < 4; ++jd) {
        int d = jd * 16 + c;
#pragma unroll
        for (int kk = 0; kk < 2; ++kk) {
          bf16x8 bv = *(const bf16x8*)((char*)Vt + ((d * 128 + kk * 64 + g * 16) ^ ((d & 7) << 4)));
          oa[jd] = __builtin_amdgcn_mfma_f32_16x16x32_bf16(ap[kk], bv, oa[jd], 0, 0, 0);
        }
      }
    }
    __syncthreads();
  }

#pragma unroll
  for (int r = 0; r < 4; ++r) {
    int q = qw + g * 4 + r;
    float inv = 1.0f / l_r[r];
    size_t base = (size_t)(b * Sc + q) * Dc + hh * DKc;
#pragma unroll
    for (int jd = 0; jd < 4; ++jd)
      o[base + jd * 16 + c] = f2b(oa[jd][r] * inv);
  }
}

// ---------------- host orchestration ----------------
extern "C" void kernel_launch(void* const* d_in, const int* in_sizes, int n_in,
                              void* d_out, int out_size, void* d_ws, size_t ws_size,
                              hipStream_t stream) {
  const float* emb  = (const float*)d_in[0];
  const float* Wq   = (const float*)d_in[1];
  const float* Wk   = (const float*)d_in[2];
  const float* Wv   = (const float*)d_in[3];
  const float* Wo   = (const float*)d_in[4];
  const float* ln1a = (const float*)d_in[5];
  const float* ln1b = (const float*)d_in[6];
  const float* ln2a = (const float*)d_in[7];
  const float* ln2b = (const float*)d_in[8];
  const float* W1   = (const float*)d_in[9];
  const float* b1   = (const float*)d_in[10];
  const float* W2   = (const float*)d_in[11];
  const float* b2   = (const float*)d_in[12];
  const float* fna  = (const float*)d_in[13];
  const float* fnb  = (const float*)d_in[14];
  const float* pb   = (const float*)d_in[15];
  const int*   x    = (const int*)d_in[16];
  float* out = (float*)d_out;

  // workspace layout (same as round 3, known good)
  float* h = (float*)d_ws;                         // T*D fp32
  ushort* xn    = (ushort*)(h + (size_t)Tc * Dc);  // T*D
  ushort* qkv   = xn + (size_t)Tc * Dc;            // T*2304
  ushort* ao    = qkv + (size_t)Tc * QKVN;         // T*D
  ushort* f1    = ao + (size_t)Tc * Dc;            // T*F
  ushort* embT  = f1 + (size_t)Tc * Fc;            // Vpad*D
  ushort* WqkvT = embT + (size_t)Vpad * Dc;        // 2304*768
  ushort* WoT   = WqkvT + (size_t)QKVN * Dc;       // 768*768
  ushort* W1T   = WoT + (size_t)Dc * Dc;           // 3072*768
  ushort* W2T   = W1T + (size_t)Fc * Dc;           // 768*3072

  embed_kernel<<<Tc, 256, 0, stream>>>(emb, x, h);
  convert_emb_kernel<<<2048, 256, 0, stream>>>(emb, embT);

  dim3 gQKV(QKVN / 128, Tc / 128);  // (18,16)
  dim3 gD64(Dc / 128, Tc / 64);     // (6,32) for BM=64 GEMMs
  dim3 gF(Fc / 128, Tc / 128);      // (24,16)
  dim3 gA(Sc / 64, Bc * Hc);        // (16,24)
  for (int l = 0; l < Lc; ++l) {
    transpose_layer_kernel<<<1728, 256, 0, stream>>>(Wq, Wk, Wv, Wo, W1, W2, l,
                                                     WqkvT, WoT, W1T, W2T);
    ln_kernel<<<Tc, 256, 0, stream>>>(h, ln1a + l * Dc, ln1b + l * Dc, xn);
    gemm_bf16<ushort, 128, false, false, false, false><<<gQKV, 256, 0, stream>>>(
        xn, WqkvT, nullptr, nullptr, qkv, Tc, QKVN, Dc, QKVN);
    flash_attn_kernel<<<gA, 256, 0, stream>>>(qkv, ao);
    gemm_bf16<float, 64, false, false, true, false><<<gD64, 256, 0, stream>>>(
        ao, WoT, nullptr, h, h, Tc, Dc, Dc, Dc);
    ln_kernel<<<Tc, 256, 0, stream>>>(h, ln2a + l * Dc, ln2b + l * Dc, xn);
    gemm_bf16<ushort, 128, true, true, false, false><<<gF, 256, 0, stream>>>(
        xn, W1T, b1 + (size_t)l * Fc, nullptr, f1, Tc, Fc, Dc, Fc);
    gemm_bf16<float, 64, true, false, true, false><<<gD64, 256, 0, stream>>>(
        f1, W2T, b2 + (size_t)l * Dc, h, h, Tc, Dc, Fc, Dc);
  }
  ln_kernel<<<Tc, 256, 0, stream>>>(h, fna, fnb, xn);
  dim3 gL(Tc / 128, Vpad / 128);  // SWAP: x = M-tile (fastest) -> B-panel reuse
  gemm_bf16<float, 128, true, false, false, true><<<gL, 256, 0, stream>>>(
      xn, embT, pb, nullptr, out, Tc, Vc, Dc, Vc);
}

// Round 7
// 2997.696 us; speedup vs baseline: 5.7870x; 1.0040x over previous
//
#include <hip/hip_runtime.h>
#include <math.h>

// Problem constants
constexpr int Lc = 12, Bc = 2, Sc = 1024, Dc = 768, Hc = 12, Fc = 3072, Vc = 50257, DKc = 64;
constexpr int Tc = Bc * Sc;   // 2048 token rows
constexpr int QKVN = 3 * Dc;  // 2304
constexpr int Vpad = 50304;   // V padded to multiple of 128

typedef __attribute__((ext_vector_type(8))) __bf16 bf16x8;
typedef __attribute__((ext_vector_type(8))) unsigned short u16x8;
typedef __attribute__((ext_vector_type(4))) float f32x4;

// ---------------- bf16 helpers (bit-level, RNE) ----------------
__device__ __forceinline__ unsigned short f2b(float f) {
  union { float f; unsigned int u; } v; v.f = f;
  unsigned int r = v.u + 0x7FFFu + ((v.u >> 16) & 1u);
  return (unsigned short)(r >> 16);
}
__device__ __forceinline__ float b2f(unsigned short u) {
  return __uint_as_float(((unsigned int)u) << 16);
}

// async global->LDS, 16B per lane. lds base must be wave-uniform; HW adds lane*16.
__device__ __forceinline__ void gload16(const void* g, void* l) {
  __builtin_amdgcn_global_load_lds((const __attribute__((address_space(1))) void*)g,
                                   (__attribute__((address_space(3))) void*)l, 16, 0, 0);
}

// ---------------- block reduction helpers (256 threads = 4 waves) ----------------
__device__ __forceinline__ float bred_sum(float v, volatile float* sb) {
#pragma unroll
  for (int o = 32; o; o >>= 1) v += __shfl_down(v, o);
  int w = threadIdx.x >> 6;
  __syncthreads();
  if ((threadIdx.x & 63) == 0) sb[w] = v;
  __syncthreads();
  return sb[0] + sb[1] + sb[2] + sb[3];
}

// ---------------- embedding + positional encoding (fp32 h) ----------------
__global__ __launch_bounds__(256) void embed_kernel(const float* __restrict__ emb,
                                                    const int* __restrict__ x,
                                                    float* __restrict__ h) {
  int t = blockIdx.x;
  int s = t & (Sc - 1);
  int tok = x[t];
  const float scale = 27.712812921102035f;  // sqrt(768)
  for (int d = threadIdx.x; d < Dc; d += 256) {
    int i = d >> 1;
    float div = __expf((float)(2 * i) * (-9.210340371976184f / (float)Dc));
    float ang = (float)s * div;
    float pe = (d & 1) ? cosf(ang) : sinf(ang);
    h[(size_t)t * Dc + d] = emb[(size_t)tok * Dc + d] * scale + pe;
  }
}

// ---------------- emb -> bf16 [Vpad][768], zero-padded ----------------
__global__ __launch_bounds__(256) void convert_emb_kernel(const float* __restrict__ emb,
                                                          ushort* __restrict__ embT) {
  const size_t total4 = (size_t)Vpad * Dc / 4;
  for (size_t i = (size_t)blockIdx.x * 256 + threadIdx.x; i < total4; i += (size_t)gridDim.x * 256) {
    size_t e = i * 4;
    int row = (int)(e / Dc);
    ushort4 w;
    if (row < Vc) {
      float4 f = *(const float4*)&emb[e];
      w.x = f2b(f.x); w.y = f2b(f.y); w.z = f2b(f.z); w.w = f2b(f.w);
    } else {
      w = make_ushort4(0, 0, 0, 0);
    }
    *(ushort4*)&embT[e] = w;
  }
}

// ---------------- per-layer weight transpose-convert: W[K,N] fp32 -> Wt[N,K] bf16 ----------------
__global__ __launch_bounds__(256) void transpose_layer_kernel(
    const float* __restrict__ Wq, const float* __restrict__ Wk, const float* __restrict__ Wv,
    const float* __restrict__ Wo, const float* __restrict__ W1, const float* __restrict__ W2,
    int l, ushort* __restrict__ WqkvT, ushort* __restrict__ WoT,
    ushort* __restrict__ W1T, ushort* __restrict__ W2T) {
  __shared__ float tile[64][65];
  int bid = blockIdx.x;
  const float* src; ushort* dst; int N, Kd, tt;
  if (bid < 432) {
    int m = bid / 144; tt = bid % 144;
    src = (m == 0 ? Wq : (m == 1 ? Wk : Wv)) + (size_t)l * Dc * Dc;
    N = Dc; Kd = Dc; dst = WqkvT + (size_t)m * Dc * Dc;
  } else if (bid < 576) {
    tt = bid - 432; src = Wo + (size_t)l * Dc * Dc; N = Dc; Kd = Dc; dst = WoT;
  } else if (bid < 1152) {
    tt = bid - 576; src = W1 + (size_t)l * Dc * Fc; N = Fc; Kd = Dc; dst = W1T;
  } else {
    tt = bid - 1152; src = W2 + (size_t)l * Fc * Dc; N = Dc; Kd = Fc; dst = W2T;
  }
  int nt = N / 64;
  int k0 = (tt / nt) * 64, n0 = (tt % nt) * 64;
  int t = threadIdx.x;
  int r0 = t >> 4, c4 = (t & 15) * 4;
#pragma unroll
  for (int rr = 0; rr < 4; ++rr) {
    int r = r0 + rr * 16;
    float4 f = *(const float4*)&src[(size_t)(k0 + r) * N + n0 + c4];
    tile[r][c4] = f.x; tile[r][c4 + 1] = f.y; tile[r][c4 + 2] = f.z; tile[r][c4 + 3] = f.w;
  }
  __syncthreads();
  int i0 = t >> 4, j4 = (t & 15) * 4;
#pragma unroll
  for (int rr = 0; rr < 4; ++rr) {
    int i = i0 + rr * 16;
    ushort4 w;
    w.x = f2b(tile[j4][i]); w.y = f2b(tile[j4 + 1][i]);
    w.z = f2b(tile[j4 + 2][i]); w.w = f2b(tile[j4 + 3][i]);
    *(ushort4*)&dst[(size_t)(n0 + i) * Kd + k0 + j4] = w;
  }
}

// ---------------- V^T materialization: qkv V-part [t][h*64+d] -> vT[hb][d][t] ----------------
__global__ __launch_bounds__(256) void vtrans_kernel(const ushort* __restrict__ qkv,
                                                     ushort* __restrict__ vT) {
  __shared__ ushort tl[64][72];
  const int st = blockIdx.x, hb = blockIdx.y;
  const int hh = hb % Hc, b = hb / Hc;
  const int t0 = st * 64;
  const int tid = threadIdx.x;
  {
    int r = tid >> 2, cg = (tid & 3) * 16;
    const ushort* src = qkv + (size_t)(b * Sc + t0 + r) * QKVN + 2 * Dc + hh * DKc + cg;
    *(u16x8*)&tl[r][cg] = *(const u16x8*)&src[0];
    *(u16x8*)&tl[r][cg + 8] = *(const u16x8*)&src[8];
  }
  __syncthreads();
  {
    int d = tid >> 2, tg = (tid & 3) * 16;
    u16x8 o0, o1;
#pragma unroll
    for (int j = 0; j < 8; ++j) { o0[j] = tl[tg + j][d]; o1[j] = tl[tg + 8 + j][d]; }
    ushort* dst = vT + (size_t)hb * DKc * Sc + (size_t)d * Sc + t0 + tg;
    *(u16x8*)&dst[0] = o0;
    *(u16x8*)&dst[8] = o1;
  }
}

// ---------------- layernorm fp32-in -> bf16-out ----------------
__global__ __launch_bounds__(256) void ln_kernel(const float* __restrict__ in,
                                                 const float* __restrict__ ga,
                                                 const float* __restrict__ be,
                                                 ushort* __restrict__ out) {
  __shared__ float sb[4];
  int t = blockIdx.x;
  const float* row = in + (size_t)t * Dc;
  int tid = threadIdx.x;
  float x0 = row[tid], x1 = row[tid + 256], x2 = row[tid + 512];
  float s = bred_sum(x0 + x1 + x2, sb);
  float mean = s * (1.0f / 768.0f);
  float d0 = x0 - mean, d1 = x1 - mean, d2 = x2 - mean;
  float vs = bred_sum(d0 * d0 + d1 * d1 + d2 * d2, sb);
  float inv = 1.0f / (sqrtf(vs * (1.0f / 767.0f)) + 1e-6f);
  ushort* orow = out + (size_t)t * Dc;
  orow[tid] = f2b(ga[tid] * d0 * inv + be[tid]);
  orow[tid + 256] = f2b(ga[tid + 256] * d1 * inv + be[tid + 256]);
  orow[tid + 512] = f2b(ga[tid + 512] * d2 * inv + be[tid + 512]);
}

// ---------------- bf16 MFMA GEMM (m97 structure, BK=64, BM in {64,128}) ----------------
// C[M,N] = A[M,K] @ Bt[N,K]^T (+bias, relu, +resid).  BN=128 fixed, 4 waves.
// SWAP: blockIdx.x = M-tile (fastest) for B-panel L2/L3 reuse (logits GEMM).
template <typename OT, int BM, bool BIAS, bool RELU, bool RESID, bool SWAP>
__global__ __launch_bounds__(256) void gemm_bf16(const ushort* __restrict__ A,
                                                 const ushort* __restrict__ Bt,
                                                 const float* __restrict__ bias,
                                                 const float* __restrict__ resid,
                                                 OT* __restrict__ C,
                                                 int M, int N, int K, int ldc) {
  constexpr int MW = BM / 64;          // m-wave count (1 or 2)
  constexpr int NW = 4 / MW;           // n-wave count (4 or 2)
  constexpr int WCOLS = 128 / NW;      // cols per wave (32 or 64)
  constexpr int NJ = WCOLS / 16;       // n-frags per wave (2 or 4)
  __shared__ __attribute__((aligned(16))) ushort sm[(BM + 128) * 64];
  ushort* As = sm;                     // [BM][64]
  ushort* Bs = sm + BM * 64;           // [128][64]
  const int tid = threadIdx.x;
  const int wid = tid >> 6, lane = tid & 63;
  const int wr = (MW == 2) ? (wid >> 1) : 0;
  const int wc = (MW == 2) ? (wid & 1) : wid;
  const int kg = lane >> 4, fr = lane & 15;
  const int bm = (SWAP ? blockIdx.x : blockIdx.y) * BM;
  const int bn = (SWAP ? blockIdx.y : blockIdx.x) * 128;

  f32x4 acc[4][NJ] = {};

  for (int k0 = 0; k0 < K; k0 += 64) {
    const ushort* Ab = A + (size_t)bm * K + k0;
    const ushort* Bb = Bt + (size_t)bn * K + k0;
    // stage A [BM][64] and B [128][64]: linear slots of 16B (8 elems)
#pragma unroll
    for (int it = 0; it < BM / 32; ++it) {
      int s = it * 256 + tid;
      int row = s >> 3, kc = (s & 7) * 8;
      gload16(Ab + (size_t)row * K + kc, &As[(it * 256 + wid * 64) * 8]);
    }
#pragma unroll
    for (int it = 0; it < 4; ++it) {
      int s = it * 256 + tid;
      int row = s >> 3, kc = (s & 7) * 8;
      gload16(Bb + (size_t)row * K + kc, &Bs[(it * 256 + wid * 64) * 8]);
    }
    __syncthreads();

#pragma unroll
    for (int hk = 0; hk < 2; ++hk) {
      bf16x8 af[4], bfr[NJ];
#pragma unroll
      for (int i = 0; i < 4; ++i)
        af[i] = *(const bf16x8*)&As[(wr * 64 + i * 16 + fr) * 64 + hk * 32 + kg * 8];
#pragma unroll
      for (int j = 0; j < NJ; ++j)
        bfr[j] = *(const bf16x8*)&Bs[(wc * WCOLS + j * 16 + fr) * 64 + hk * 32 + kg * 8];
#pragma unroll
      for (int i = 0; i < 4; ++i)
#pragma unroll
        for (int j = 0; j < NJ; ++j)
          acc[i][j] = __builtin_amdgcn_mfma_f32_16x16x32_bf16(af[i], bfr[j], acc[i][j], 0, 0, 0);
    }
    __syncthreads();
  }

  const int r0 = kg * 4;
#pragma unroll
  for (int i = 0; i < 4; ++i) {
    int mbase = bm + wr * 64 + i * 16 + r0;
#pragma unroll
    for (int j = 0; j < NJ; ++j) {
      int n = bn + wc * WCOLS + j * 16 + fr;
      if (n < N) {
        float bv = BIAS ? bias[n] : 0.0f;
#pragma unroll
        for (int r = 0; r < 4; ++r) {
          float v = acc[i][j][r] + bv;
          if (RELU) v = fmaxf(v, 0.0f);
          size_t idx = (size_t)(mbase + r) * ldc + n;
          if (RESID) v += resid[idx];
          if constexpr (sizeof(OT) == 2) C[idx] = (OT)f2b(v);
          else C[idx] = (OT)v;
        }
      }
    }
  }
}

// ---------------- flash attention: 64 q-rows/block, KVBLK=128, gload16 staging ----------------
// qkv: [T][2304] bf16 (Q|K|V). vT: [24][64][1024] bf16. o: [T][768] bf16.
__global__ __launch_bounds__(256) void flash_attn_kernel(const ushort* __restrict__ qkv,
                                                         const ushort* __restrict__ vT,
                                                         ushort* __restrict__ o) {
  const int qt = gridDim.x - 1 - blockIdx.x;  // long blocks dispatch first
  const int hb = blockIdx.y;                  // b*H + h
  const int hh = hb % Hc, b = hb / Hc;
  const int tid = threadIdx.x;
  const int w = tid >> 6, lane = tid & 63;
  const int g = lane >> 4, c = lane & 15;

  __shared__ __attribute__((aligned(16))) ushort Ks[128 * 64];    // [kv][dk] swz
  __shared__ __attribute__((aligned(16))) ushort Vs[64 * 128];    // [d][kv] swz
  __shared__ __attribute__((aligned(16))) ushort Ps[4][16 * 128]; // per-wave P swz

  const int q0 = qt * 64;
  const int qw = q0 + w * 16;

  bf16x8 aq[2];
  {
    const size_t qrow = (size_t)(b * Sc + qw + c) * QKVN + hh * DKc;
#pragma unroll
    for (int kk = 0; kk < 2; ++kk)
      aq[kk] = *(const bf16x8*)&qkv[qrow + kk * 32 + g * 8];
  }

  float m_r[4], l_r[4];
  f32x4 oa[4] = {};
#pragma unroll
  for (int r = 0; r < 4; ++r) { m_r[r] = -1e30f; l_r[r] = 0.f; }

  const ushort* kbase = qkv + (size_t)b * Sc * QKVN + Dc + hh * DKc;
  const ushort* vbase = vT + (size_t)hb * DKc * Sc;
  const float kS = 0.18033688011112042f;  // 0.125 * log2(e)

  const int KT = (qt + 2) >> 1;
  for (int t = 0; t < KT; ++t) {
    const int kv0 = t * 128;
    // ---- stage K [128][64] swizzled via pre-swizzled source (linear LDS dest)
#pragma unroll
    for (int it = 0; it < 4; ++it) {
      int s = it * 256 + tid;
      int kv = s >> 3;
      int dkb = ((s & 7) * 16) ^ ((kv & 7) << 4);   // byte offset within row
      gload16(kbase + (size_t)(kv0 + kv) * QKVN + (dkb >> 1),
              (char*)Ks + (it * 256 + w * 64) * 16);
    }
    // ---- stage V^T [64][128] swizzled via pre-swizzled source
#pragma unroll
    for (int it = 0; it < 4; ++it) {
      int s = it * 256 + tid;
      int d = s >> 4;
      int kvb = ((s & 15) * 16) ^ ((d & 7) << 4);
      gload16(vbase + (size_t)d * Sc + kv0 + (kvb >> 1),
              (char*)Vs + (it * 256 + w * 64) * 16);
    }
    __syncthreads();

    // ---- QK^T: S[16q x 128kv] per wave
    f32x4 sacc[8] = {};
#pragma unroll
    for (int jn = 0; jn < 8; ++jn) {
      int kvl = jn * 16 + c;
#pragma unroll
      for (int kk = 0; kk < 2; ++kk) {
        bf16x8 bk = *(const bf16x8*)((char*)Ks + ((kvl * 128 + kk * 64 + g * 16) ^ ((kvl & 7) << 4)));
        sacc[jn] = __builtin_amdgcn_mfma_f32_16x16x32_bf16(aq[kk], bk, sacc[jn], 0, 0, 0);
      }
    }

    // ---- scale (log2 domain) + causal mask on diagonal tile only
#pragma unroll
    for (int jn = 0; jn < 8; ++jn)
#pragma unroll
      for (int r = 0; r < 4; ++r) sacc[jn][r] *= kS;
    if (t == KT - 1) {
#pragma unroll
      for (int jn = 0; jn < 8; ++jn) {
        int kvg = kv0 + jn * 16 + c;
#pragma unroll
        for (int r = 0; r < 4; ++r)
          if (kvg > qw + g * 4 + r) sacc[jn][r] = -1e30f;
      }
    }

    // ---- online softmax (exp2 domain), per output row r
#pragma unroll
    for (int r = 0; r < 4; ++r) {
      float mx = sacc[0][r];
#pragma unroll
      for (int jn = 1; jn < 8; ++jn) mx = fmaxf(mx, sacc[jn][r]);
#pragma unroll
      for (int off = 1; off < 16; off <<= 1) mx = fmaxf(mx, __shfl_xor(mx, off));
      float mnew = fmaxf(m_r[r], mx);
      float sf = exp2f(m_r[r] - mnew);
      m_r[r] = mnew;
      float rs = 0.f;
#pragma unroll
      for (int jn = 0; jn < 8; ++jn) {
        float e = exp2f(sacc[jn][r] - mnew);
        sacc[jn][r] = e;
        rs += e;
      }
#pragma unroll
      for (int off = 1; off < 16; off <<= 1) rs += __shfl_xor(rs, off);
      l_r[r] = l_r[r] * sf + rs;
#pragma unroll
      for (int jd = 0; jd < 4; ++jd) oa[jd][r] *= sf;
    }

    // ---- P -> bf16 -> per-wave LDS (swizzled, row stride 256B); wave-local
    {
      ushort* pw = Ps[w];
#pragma unroll
      for (int jn = 0; jn < 8; ++jn)
#pragma unroll
        for (int r = 0; r < 4; ++r) {
          int row = g * 4 + r, col = jn * 16 + c;
          *(ushort*)((char*)pw + ((row * 256 + col * 2) ^ ((row & 7) << 4))) = f2b(sacc[jn][r]);
        }
      bf16x8 ap[4];
#pragma unroll
      for (int kk = 0; kk < 4; ++kk)
        ap[kk] = *(const bf16x8*)((char*)pw + ((c * 256 + kk * 64 + g * 16) ^ ((c & 7) << 4)));
      // ---- PV: O[16q x 64d] += P @ V
#pragma unroll
      for (int jd = 0; jd < 4; ++jd) {
        int d = jd * 16 + c;
#pragma unroll
        for (int kk = 0; kk < 4; ++kk) {
          bf16x8 bv = *(const bf16x8*)((char*)Vs + ((d * 256 + kk * 64 + g * 16) ^ ((d & 7) << 4)));
          oa[jd] = __builtin_amdgcn_mfma_f32_16x16x32_bf16(ap[kk], bv, oa[jd], 0, 0, 0);
        }
      }
    }
    __syncthreads();
  }

#pragma unroll
  for (int r = 0; r < 4; ++r) {
    int q = qw + g * 4 + r;
    float inv = 1.0f / l_r[r];
    size_t base = (size_t)(b * Sc + q) * Dc + hh * DKc;
#pragma unroll
    for (int jd = 0; jd < 4; ++jd)
      o[base + jd * 16 + c] = f2b(oa[jd][r] * inv);
  }
}

// ---------------- host orchestration ----------------
extern "C" void kernel_launch(void* const* d_in, const int* in_sizes, int n_in,
                              void* d_out, int out_size, void* d_ws, size_t ws_size,
                              hipStream_t stream) {
  const float* emb  = (const float*)d_in[0];
  const float* Wq   = (const float*)d_in[1];
  const float* Wk   = (const float*)d_in[2];
  const float* Wv   = (const float*)d_in[3];
  const float* Wo   = (const float*)d_in[4];
  const float* ln1a = (const float*)d_in[5];
  const float* ln1b = (const float*)d_in[6];
  const float* ln2a = (const float*)d_in[7];
  const float* ln2b = (const float*)d_in[8];
  const float* W1   = (const float*)d_in[9];
  const float* b1   = (const float*)d_in[10];
  const float* W2   = (const float*)d_in[11];
  const float* b2   = (const float*)d_in[12];
  const float* fna  = (const float*)d_in[13];
  const float* fnb  = (const float*)d_in[14];
  const float* pb   = (const float*)d_in[15];
  const int*   x    = (const int*)d_in[16];
  float* out = (float*)d_out;

  // workspace layout
  float* h = (float*)d_ws;                         // T*D fp32
  ushort* xn    = (ushort*)(h + (size_t)Tc * Dc);  // T*D
  ushort* qkv   = xn + (size_t)Tc * Dc;            // T*2304
  ushort* ao    = qkv + (size_t)Tc * QKVN;         // T*D
  ushort* f1    = ao + (size_t)Tc * Dc;            // T*F
  ushort* vT    = f1 + (size_t)Tc * Fc;            // 24*64*1024
  ushort* embT  = vT + (size_t)Bc * Hc * DKc * Sc; // Vpad*D
  ushort* WqkvT = embT + (size_t)Vpad * Dc;        // 2304*768
  ushort* WoT   = WqkvT + (size_t)QKVN * Dc;       // 768*768
  ushort* W1T   = WoT + (size_t)Dc * Dc;           // 3072*768
  ushort* W2T   = W1T + (size_t)Fc * Dc;           // 768*3072

  embed_kernel<<<Tc, 256, 0, stream>>>(emb, x, h);
  convert_emb_kernel<<<2048, 256, 0, stream>>>(emb, embT);

  dim3 gQKV(QKVN / 128, Tc / 128);  // (18,16)
  dim3 gD64(Dc / 128, Tc / 64);     // (6,32) for BM=64 GEMMs
  dim3 gF(Fc / 128, Tc / 128);      // (24,16)
  dim3 gA(Sc / 64, Bc * Hc);        // (16,24)
  dim3 gV(Sc / 64, Bc * Hc);        // (16,24)
  for (int l = 0; l < Lc; ++l) {
    transpose_layer_kernel<<<1728, 256, 0, stream>>>(Wq, Wk, Wv, Wo, W1, W2, l,
                                                     WqkvT, WoT, W1T, W2T);
    ln_kernel<<<Tc, 256, 0, stream>>>(h, ln1a + l * Dc, ln1b + l * Dc, xn);
    gemm_bf16<ushort, 128, false, false, false, false><<<gQKV, 256, 0, stream>>>(
        xn, WqkvT, nullptr, nullptr, qkv, Tc, QKVN, Dc, QKVN);
    vtrans_kernel<<<gV, 256, 0, stream>>>(qkv, vT);
    flash_attn_kernel<<<gA, 256, 0, stream>>>(qkv, vT, ao);
    gemm_bf16<float, 64, false, false, true, false><<<gD64, 256, 0, stream>>>(
        ao, WoT, nullptr, h, h, Tc, Dc, Dc, Dc);
    ln_kernel<<<Tc, 256, 0, stream>>>(h, ln2a + l * Dc, ln2b + l * Dc, xn);
    gemm_bf16<ushort, 128, true, true, false, false><<<gF, 256, 0, stream>>>(
        xn, W1T, b1 + (size_t)l * Fc, nullptr, f1, Tc, Fc, Dc, Fc);
    gemm_bf16<float, 64, true, false, true, false><<<gD64, 256, 0, stream>>>(
        f1, W2T, b2 + (size_t)l * Dc, h, h, Tc, Dc, Fc, Dc);
  }
  ln_kernel<<<Tc, 256, 0, stream>>>(h, fna, fnb, xn);
  dim3 gL(Tc / 128, Vpad / 128);  // SWAP: x = M-tile (fastest) -> B-panel reuse
  gemm_bf16<float, 128, true, false, false, true><<<gL, 256, 0, stream>>>(
      xn, embT, pb, nullptr, out, Tc, Vc, Dc, Vc);
}

// Round 8
// 2737.162 us; speedup vs baseline: 6.3378x; 1.0952x over previous
//
#include <hip/hip_runtime.h>
#include <math.h>

// Problem constants
constexpr int Lc = 12, Bc = 2, Sc = 1024, Dc = 768, Hc = 12, Fc = 3072, Vc = 50257, DKc = 64;
constexpr int Tc = Bc * Sc;   // 2048 token rows
constexpr int QKVN = 3 * Dc;  // 2304
constexpr int Vpad = 50304;   // V padded to multiple of 128

typedef __attribute__((ext_vector_type(8))) __bf16 bf16x8;
typedef __attribute__((ext_vector_type(8))) unsigned short u16x8;
typedef __attribute__((ext_vector_type(4))) float f32x4;

// ---------------- bf16 helpers (bit-level, RNE) ----------------
__device__ __forceinline__ unsigned short f2b(float f) {
  union { float f; unsigned int u; } v; v.f = f;
  unsigned int r = v.u + 0x7FFFu + ((v.u >> 16) & 1u);
  return (unsigned short)(r >> 16);
}
__device__ __forceinline__ float b2f(unsigned short u) {
  return __uint_as_float(((unsigned int)u) << 16);
}

// async global->LDS, 16B per lane. lds base must be wave-uniform; HW adds lane*16.
__device__ __forceinline__ void gload16(const void* g, void* l) {
  __builtin_amdgcn_global_load_lds((const __attribute__((address_space(1))) void*)g,
                                   (__attribute__((address_space(3))) void*)l, 16, 0, 0);
}

// ---------------- block reduction helpers (256 threads = 4 waves) ----------------
__device__ __forceinline__ float bred_sum(float v, volatile float* sb) {
#pragma unroll
  for (int o = 32; o; o >>= 1) v += __shfl_down(v, o);
  int w = threadIdx.x >> 6;
  __syncthreads();
  if ((threadIdx.x & 63) == 0) sb[w] = v;
  __syncthreads();
  return sb[0] + sb[1] + sb[2] + sb[3];
}

// ---------------- embedding + positional encoding (fp32 h) ----------------
__global__ __launch_bounds__(256) void embed_kernel(const float* __restrict__ emb,
                                                    const int* __restrict__ x,
                                                    float* __restrict__ h) {
  int t = blockIdx.x;
  int s = t & (Sc - 1);
  int tok = x[t];
  const float scale = 27.712812921102035f;  // sqrt(768)
  for (int d = threadIdx.x; d < Dc; d += 256) {
    int i = d >> 1;
    float div = __expf((float)(2 * i) * (-9.210340371976184f / (float)Dc));
    float ang = (float)s * div;
    float pe = (d & 1) ? cosf(ang) : sinf(ang);
    h[(size_t)t * Dc + d] = emb[(size_t)tok * Dc + d] * scale + pe;
  }
}

// ---------------- emb -> bf16 [Vpad][768], zero-padded ----------------
__global__ __launch_bounds__(256) void convert_emb_kernel(const float* __restrict__ emb,
                                                          ushort* __restrict__ embT) {
  const size_t total4 = (size_t)Vpad * Dc / 4;
  for (size_t i = (size_t)blockIdx.x * 256 + threadIdx.x; i < total4; i += (size_t)gridDim.x * 256) {
    size_t e = i * 4;
    int row = (int)(e / Dc);
    ushort4 w;
    if (row < Vc) {
      float4 f = *(const float4*)&emb[e];
      w.x = f2b(f.x); w.y = f2b(f.y); w.z = f2b(f.z); w.w = f2b(f.w);
    } else {
      w = make_ushort4(0, 0, 0, 0);
    }
    *(ushort4*)&embT[e] = w;
  }
}

// ---------------- per-layer weight transpose-convert: W[K,N] fp32 -> Wt[N,K] bf16 ----------------
__global__ __launch_bounds__(256) void transpose_layer_kernel(
    const float* __restrict__ Wq, const float* __restrict__ Wk, const float* __restrict__ Wv,
    const float* __restrict__ Wo, const float* __restrict__ W1, const float* __restrict__ W2,
    int l, ushort* __restrict__ WqkvT, ushort* __restrict__ WoT,
    ushort* __restrict__ W1T, ushort* __restrict__ W2T) {
  __shared__ float tile[64][65];
  int bid = blockIdx.x;
  const float* src; ushort* dst; int N, Kd, tt;
  if (bid < 432) {
    int m = bid / 144; tt = bid % 144;
    src = (m == 0 ? Wq : (m == 1 ? Wk : Wv)) + (size_t)l * Dc * Dc;
    N = Dc; Kd = Dc; dst = WqkvT + (size_t)m * Dc * Dc;
  } else if (bid < 576) {
    tt = bid - 432; src = Wo + (size_t)l * Dc * Dc; N = Dc; Kd = Dc; dst = WoT;
  } else if (bid < 1152) {
    tt = bid - 576; src = W1 + (size_t)l * Dc * Fc; N = Fc; Kd = Dc; dst = W1T;
  } else {
    tt = bid - 1152; src = W2 + (size_t)l * Fc * Dc; N = Dc; Kd = Fc; dst = W2T;
  }
  int nt = N / 64;
  int k0 = (tt / nt) * 64, n0 = (tt % nt) * 64;
  int t = threadIdx.x;
  int r0 = t >> 4, c4 = (t & 15) * 4;
#pragma unroll
  for (int rr = 0; rr < 4; ++rr) {
    int r = r0 + rr * 16;
    float4 f = *(const float4*)&src[(size_t)(k0 + r) * N + n0 + c4];
    tile[r][c4] = f.x; tile[r][c4 + 1] = f.y; tile[r][c4 + 2] = f.z; tile[r][c4 + 3] = f.w;
  }
  __syncthreads();
  int i0 = t >> 4, j4 = (t & 15) * 4;
#pragma unroll
  for (int rr = 0; rr < 4; ++rr) {
    int i = i0 + rr * 16;
    ushort4 w;
    w.x = f2b(tile[j4][i]); w.y = f2b(tile[j4 + 1][i]);
    w.z = f2b(tile[j4 + 2][i]); w.w = f2b(tile[j4 + 3][i]);
    *(ushort4*)&dst[(size_t)(n0 + i) * Kd + k0 + j4] = w;
  }
}

// ---------------- V^T materialization: qkv V-part [t][h*64+d] -> vT[hb][d][t] ----------------
__global__ __launch_bounds__(256) void vtrans_kernel(const ushort* __restrict__ qkv,
                                                     ushort* __restrict__ vT) {
  __shared__ ushort tl[64][72];
  const int st = blockIdx.x, hb = blockIdx.y;
  const int hh = hb % Hc, b = hb / Hc;
  const int t0 = st * 64;
  const int tid = threadIdx.x;
  {
    int r = tid >> 2, cg = (tid & 3) * 16;
    const ushort* src = qkv + (size_t)(b * Sc + t0 + r) * QKVN + 2 * Dc + hh * DKc + cg;
    *(u16x8*)&tl[r][cg] = *(const u16x8*)&src[0];
    *(u16x8*)&tl[r][cg + 8] = *(const u16x8*)&src[8];
  }
  __syncthreads();
  {
    int d = tid >> 2, tg = (tid & 3) * 16;
    u16x8 o0, o1;
#pragma unroll
    for (int j = 0; j < 8; ++j) { o0[j] = tl[tg + j][d]; o1[j] = tl[tg + 8 + j][d]; }
    ushort* dst = vT + (size_t)hb * DKc * Sc + (size_t)d * Sc + t0 + tg;
    *(u16x8*)&dst[0] = o0;
    *(u16x8*)&dst[8] = o1;
  }
}

// ---------------- layernorm fp32-in -> bf16-out ----------------
__global__ __launch_bounds__(256) void ln_kernel(const float* __restrict__ in,
                                                 const float* __restrict__ ga,
                                                 const float* __restrict__ be,
                                                 ushort* __restrict__ out) {
  __shared__ float sb[4];
  int t = blockIdx.x;
  const float* row = in + (size_t)t * Dc;
  int tid = threadIdx.x;
  float x0 = row[tid], x1 = row[tid + 256], x2 = row[tid + 512];
  float s = bred_sum(x0 + x1 + x2, sb);
  float mean = s * (1.0f / 768.0f);
  float d0 = x0 - mean, d1 = x1 - mean, d2 = x2 - mean;
  float vs = bred_sum(d0 * d0 + d1 * d1 + d2 * d2, sb);
  float inv = 1.0f / (sqrtf(vs * (1.0f / 767.0f)) + 1e-6f);
  ushort* orow = out + (size_t)t * Dc;
  orow[tid] = f2b(ga[tid] * d0 * inv + be[tid]);
  orow[tid + 256] = f2b(ga[tid + 256] * d1 * inv + be[tid + 256]);
  orow[tid + 512] = f2b(ga[tid + 512] * d2 * inv + be[tid + 512]);
}

// ---------------- bf16 MFMA GEMM (BK=64, XOR-swizzled LDS, BM in {64,128}) ----------------
// C[M,N] = A[M,K] @ Bt[N,K]^T (+bias, relu, +resid).  BN=128 fixed, 4 waves.
// LDS rows are 128B; byte ^= ((row&7)<<4) swizzle applied on BOTH stage-source
// and read side (global_load_lds dest stays linear — rule 21).
// SWAP: blockIdx.x = M-tile (fastest) for B-panel L2/L3 reuse (logits GEMM).
template <typename OT, int BM, bool BIAS, bool RELU, bool RESID, bool SWAP>
__global__ __launch_bounds__(256) void gemm_bf16(const ushort* __restrict__ A,
                                                 const ushort* __restrict__ Bt,
                                                 const float* __restrict__ bias,
                                                 const float* __restrict__ resid,
                                                 OT* __restrict__ C,
                                                 int M, int N, int K, int ldc) {
  constexpr int MW = BM / 64;          // m-wave count (1 or 2)
  constexpr int NW = 4 / MW;           // n-wave count (4 or 2)
  constexpr int WCOLS = 128 / NW;      // cols per wave (32 or 64)
  constexpr int NJ = WCOLS / 16;       // n-frags per wave (2 or 4)
  __shared__ __attribute__((aligned(16))) ushort sm[(BM + 128) * 64];
  ushort* As = sm;                     // [BM][64] swz
  ushort* Bs = sm + BM * 64;           // [128][64] swz
  const int tid = threadIdx.x;
  const int wid = tid >> 6, lane = tid & 63;
  const int wr = (MW == 2) ? (wid >> 1) : 0;
  const int wc = (MW == 2) ? (wid & 1) : wid;
  const int kg = lane >> 4, fr = lane & 15;
  const int bm = (SWAP ? blockIdx.x : blockIdx.y) * BM;
  const int bn = (SWAP ? blockIdx.y : blockIdx.x) * 128;

  f32x4 acc[4][NJ] = {};

  for (int k0 = 0; k0 < K; k0 += 64) {
    const ushort* Ab = A + (size_t)bm * K + k0;
    const ushort* Bb = Bt + (size_t)bn * K + k0;
    // stage A [BM][64] and B [128][64]: linear 16B slots, source pre-swizzled
#pragma unroll
    for (int it = 0; it < BM / 32; ++it) {
      int s = it * 256 + tid;
      int row = s >> 3;
      int cb = ((s & 7) * 16) ^ ((row & 7) << 4);   // swizzled byte col in row
      gload16(Ab + (size_t)row * K + (cb >> 1), (char*)As + (it * 256 + wid * 64) * 16);
    }
#pragma unroll
    for (int it = 0; it < 4; ++it) {
      int s = it * 256 + tid;
      int row = s >> 3;
      int cb = ((s & 7) * 16) ^ ((row & 7) << 4);
      gload16(Bb + (size_t)row * K + (cb >> 1), (char*)Bs + (it * 256 + wid * 64) * 16);
    }
    __syncthreads();

#pragma unroll
    for (int hk = 0; hk < 2; ++hk) {
      bf16x8 af[4], bfr[NJ];
#pragma unroll
      for (int i = 0; i < 4; ++i) {
        int row = wr * 64 + i * 16 + fr;
        af[i] = *(const bf16x8*)((char*)As + ((row * 128 + hk * 64 + kg * 16) ^ ((row & 7) << 4)));
      }
#pragma unroll
      for (int j = 0; j < NJ; ++j) {
        int row = wc * WCOLS + j * 16 + fr;
        bfr[j] = *(const bf16x8*)((char*)Bs + ((row * 128 + hk * 64 + kg * 16) ^ ((row & 7) << 4)));
      }
#pragma unroll
      for (int i = 0; i < 4; ++i)
#pragma unroll
        for (int j = 0; j < NJ; ++j)
          acc[i][j] = __builtin_amdgcn_mfma_f32_16x16x32_bf16(af[i], bfr[j], acc[i][j], 0, 0, 0);
    }
    __syncthreads();
  }

  const int r0 = kg * 4;
#pragma unroll
  for (int i = 0; i < 4; ++i) {
    int mbase = bm + wr * 64 + i * 16 + r0;
#pragma unroll
    for (int j = 0; j < NJ; ++j) {
      int n = bn + wc * WCOLS + j * 16 + fr;
      if (n < N) {
        float bv = BIAS ? bias[n] : 0.0f;
#pragma unroll
        for (int r = 0; r < 4; ++r) {
          float v = acc[i][j][r] + bv;
          if (RELU) v = fmaxf(v, 0.0f);
          size_t idx = (size_t)(mbase + r) * ldc + n;
          if (RESID) v += resid[idx];
          if constexpr (sizeof(OT) == 2) C[idx] = (OT)f2b(v);
          else C[idx] = (OT)v;
        }
      }
    }
  }
}

// ---------------- flash attention: 64 q-rows/block, KVBLK=128, gload16 staging ----------------
// qkv: [T][2304] bf16 (Q|K|V). vT: [24][64][1024] bf16. o: [T][768] bf16.
__global__ __launch_bounds__(256) void flash_attn_kernel(const ushort* __restrict__ qkv,
                                                         const ushort* __restrict__ vT,
                                                         ushort* __restrict__ o) {
  const int qt = gridDim.x - 1 - blockIdx.x;  // long blocks dispatch first
  const int hb = blockIdx.y;                  // b*H + h
  const int hh = hb % Hc, b = hb / Hc;
  const int tid = threadIdx.x;
  const int w = tid >> 6, lane = tid & 63;
  const int g = lane >> 4, c = lane & 15;

  __shared__ __attribute__((aligned(16))) ushort Ks[128 * 64];    // [kv][dk] swz
  __shared__ __attribute__((aligned(16))) ushort Vs[64 * 128];    // [d][kv] swz
  __shared__ __attribute__((aligned(16))) ushort Ps[4][16 * 128]; // per-wave P swz

  const int q0 = qt * 64;
  const int qw = q0 + w * 16;

  bf16x8 aq[2];
  {
    const size_t qrow = (size_t)(b * Sc + qw + c) * QKVN + hh * DKc;
#pragma unroll
    for (int kk = 0; kk < 2; ++kk)
      aq[kk] = *(const bf16x8*)&qkv[qrow + kk * 32 + g * 8];
  }

  float m_r[4], l_r[4];
  f32x4 oa[4] = {};
#pragma unroll
  for (int r = 0; r < 4; ++r) { m_r[r] = -1e30f; l_r[r] = 0.f; }

  const ushort* kbase = qkv + (size_t)b * Sc * QKVN + Dc + hh * DKc;
  const ushort* vbase = vT + (size_t)hb * DKc * Sc;
  const float kS = 0.18033688011112042f;  // 0.125 * log2(e)

  const int KT = (qt + 2) >> 1;
  for (int t = 0; t < KT; ++t) {
    const int kv0 = t * 128;
    // ---- stage K [128][64] swizzled via pre-swizzled source (linear LDS dest)
#pragma unroll
    for (int it = 0; it < 4; ++it) {
      int s = it * 256 + tid;
      int kv = s >> 3;
      int dkb = ((s & 7) * 16) ^ ((kv & 7) << 4);   // byte offset within row
      gload16(kbase + (size_t)(kv0 + kv) * QKVN + (dkb >> 1),
              (char*)Ks + (it * 256 + w * 64) * 16);
    }
    // ---- stage V^T [64][128] swizzled via pre-swizzled source
#pragma unroll
    for (int it = 0; it < 4; ++it) {
      int s = it * 256 + tid;
      int d = s >> 4;
      int kvb = ((s & 15) * 16) ^ ((d & 7) << 4);
      gload16(vbase + (size_t)d * Sc + kv0 + (kvb >> 1),
              (char*)Vs + (it * 256 + w * 64) * 16);
    }
    __syncthreads();

    // ---- QK^T: S[16q x 128kv] per wave
    f32x4 sacc[8] = {};
#pragma unroll
    for (int jn = 0; jn < 8; ++jn) {
      int kvl = jn * 16 + c;
#pragma unroll
      for (int kk = 0; kk < 2; ++kk) {
        bf16x8 bk = *(const bf16x8*)((char*)Ks + ((kvl * 128 + kk * 64 + g * 16) ^ ((kvl & 7) << 4)));
        sacc[jn] = __builtin_amdgcn_mfma_f32_16x16x32_bf16(aq[kk], bk, sacc[jn], 0, 0, 0);
      }
    }

    // ---- scale (log2 domain) + causal mask on diagonal tile only
#pragma unroll
    for (int jn = 0; jn < 8; ++jn)
#pragma unroll
      for (int r = 0; r < 4; ++r) sacc[jn][r] *= kS;
    if (t == KT - 1) {
#pragma unroll
      for (int jn = 0; jn < 8; ++jn) {
        int kvg = kv0 + jn * 16 + c;
#pragma unroll
        for (int r = 0; r < 4; ++r)
          if (kvg > qw + g * 4 + r) sacc[jn][r] = -1e30f;
      }
    }

    // ---- online softmax (exp2 domain), per output row r
#pragma unroll
    for (int r = 0; r < 4; ++r) {
      float mx = sacc[0][r];
#pragma unroll
      for (int jn = 1; jn < 8; ++jn) mx = fmaxf(mx, sacc[jn][r]);
#pragma unroll
      for (int off = 1; off < 16; off <<= 1) mx = fmaxf(mx, __shfl_xor(mx, off));
      float mnew = fmaxf(m_r[r], mx);
      float sf = exp2f(m_r[r] - mnew);
      m_r[r] = mnew;
      float rs = 0.f;
#pragma unroll
      for (int jn = 0; jn < 8; ++jn) {
        float e = exp2f(sacc[jn][r] - mnew);
        sacc[jn][r] = e;
        rs += e;
      }
#pragma unroll
      for (int off = 1; off < 16; off <<= 1) rs += __shfl_xor(rs, off);
      l_r[r] = l_r[r] * sf + rs;
#pragma unroll
      for (int jd = 0; jd < 4; ++jd) oa[jd][r] *= sf;
    }

    // ---- P -> bf16 -> per-wave LDS (swizzled, row stride 256B); wave-local
    {
      ushort* pw = Ps[w];
#pragma unroll
      for (int jn = 0; jn < 8; ++jn)
#pragma unroll
        for (int r = 0; r < 4; ++r) {
          int row = g * 4 + r, col = jn * 16 + c;
          *(ushort*)((char*)pw + ((row * 256 + col * 2) ^ ((row & 7) << 4))) = f2b(sacc[jn][r]);
        }
      bf16x8 ap[4];
#pragma unroll
      for (int kk = 0; kk < 4; ++kk)
        ap[kk] = *(const bf16x8*)((char*)pw + ((c * 256 + kk * 64 + g * 16) ^ ((c & 7) << 4)));
      // ---- PV: O[16q x 64d] += P @ V
#pragma unroll
      for (int jd = 0; jd < 4; ++jd) {
        int d = jd * 16 + c;
#pragma unroll
        for (int kk = 0; kk < 4; ++kk) {
          bf16x8 bv = *(const bf16x8*)((char*)Vs + ((d * 256 + kk * 64 + g * 16) ^ ((d & 7) << 4)));
          oa[jd] = __builtin_amdgcn_mfma_f32_16x16x32_bf16(ap[kk], bv, oa[jd], 0, 0, 0);
        }
      }
    }
    __syncthreads();
  }

#pragma unroll
  for (int r = 0; r < 4; ++r) {
    int q = qw + g * 4 + r;
    float inv = 1.0f / l_r[r];
    size_t base = (size_t)(b * Sc + q) * Dc + hh * DKc;
#pragma unroll
    for (int jd = 0; jd < 4; ++jd)
      o[base + jd * 16 + c] = f2b(oa[jd][r] * inv);
  }
}

// ---------------- host orchestration ----------------
extern "C" void kernel_launch(void* const* d_in, const int* in_sizes, int n_in,
                              void* d_out, int out_size, void* d_ws, size_t ws_size,
                              hipStream_t stream) {
  const float* emb  = (const float*)d_in[0];
  const float* Wq   = (const float*)d_in[1];
  const float* Wk   = (const float*)d_in[2];
  const float* Wv   = (const float*)d_in[3];
  const float* Wo   = (const float*)d_in[4];
  const float* ln1a = (const float*)d_in[5];
  const float* ln1b = (const float*)d_in[6];
  const float* ln2a = (const float*)d_in[7];
  const float* ln2b = (const float*)d_in[8];
  const float* W1   = (const float*)d_in[9];
  const float* b1   = (const float*)d_in[10];
  const float* W2   = (const float*)d_in[11];
  const float* b2   = (const float*)d_in[12];
  const float* fna  = (const float*)d_in[13];
  const float* fnb  = (const float*)d_in[14];
  const float* pb   = (const float*)d_in[15];
  const int*   x    = (const int*)d_in[16];
  float* out = (float*)d_out;

  // workspace layout
  float* h = (float*)d_ws;                         // T*D fp32
  ushort* xn    = (ushort*)(h + (size_t)Tc * Dc);  // T*D
  ushort* qkv   = xn + (size_t)Tc * Dc;            // T*2304
  ushort* ao    = qkv + (size_t)Tc * QKVN;         // T*D
  ushort* f1    = ao + (size_t)Tc * Dc;            // T*F
  ushort* vT    = f1 + (size_t)Tc * Fc;            // 24*64*1024
  ushort* embT  = vT + (size_t)Bc * Hc * DKc * Sc; // Vpad*D
  ushort* WqkvT = embT + (size_t)Vpad * Dc;        // 2304*768
  ushort* WoT   = WqkvT + (size_t)QKVN * Dc;       // 768*768
  ushort* W1T   = WoT + (size_t)Dc * Dc;           // 3072*768
  ushort* W2T   = W1T + (size_t)Fc * Dc;           // 768*3072

  embed_kernel<<<Tc, 256, 0, stream>>>(emb, x, h);
  convert_emb_kernel<<<2048, 256, 0, stream>>>(emb, embT);

  dim3 gQKV(QKVN / 128, Tc / 128);  // (18,16)
  dim3 gD64(Dc / 128, Tc / 64);     // (6,32) for BM=64 GEMMs
  dim3 gF(Fc / 128, Tc / 128);      // (24,16)
  dim3 gA(Sc / 64, Bc * Hc);        // (16,24)
  dim3 gV(Sc / 64, Bc * Hc);        // (16,24)
  for (int l = 0; l < Lc; ++l) {
    transpose_layer_kernel<<<1728, 256, 0, stream>>>(Wq, Wk, Wv, Wo, W1, W2, l,
                                                     WqkvT, WoT, W1T, W2T);
    ln_kernel<<<Tc, 256, 0, stream>>>(h, ln1a + l * Dc, ln1b + l * Dc, xn);
    gemm_bf16<ushort, 128, false, false, false, false><<<gQKV, 256, 0, stream>>>(
        xn, WqkvT, nullptr, nullptr, qkv, Tc, QKVN, Dc, QKVN);
    vtrans_kernel<<<gV, 256, 0, stream>>>(qkv, vT);
    flash_attn_kernel<<<gA, 256, 0, stream>>>(qkv, vT, ao);
    gemm_bf16<float, 64, false, false, true, false><<<gD64, 256, 0, stream>>>(
        ao, WoT, nullptr, h, h, Tc, Dc, Dc, Dc);
    ln_kernel<<<Tc, 256, 0, stream>>>(h, ln2a + l * Dc, ln2b + l * Dc, xn);
    gemm_bf16<ushort, 128, true, true, false, false><<<gF, 256, 0, stream>>>(
        xn, W1T, b1 + (size_t)l * Fc, nullptr, f1, Tc, Fc, Dc, Fc);
    gemm_bf16<float, 64, true, false, true, false><<<gD64, 256, 0, stream>>>(
        f1, W2T, b2 + (size_t)l * Dc, h, h, Tc, Dc, Fc, Dc);
  }
  ln_kernel<<<Tc, 256, 0, stream>>>(h, fna, fnb, xn);
  dim3 gL(Tc / 128, Vpad / 128);  // SWAP: x = M-tile (fastest) -> B-panel reuse
  gemm_bf16<float, 128, true, false, false, true><<<gL, 256, 0, stream>>>(
      xn, embT, pb, nullptr, out, Tc, Vc, Dc, Vc);
}